// Round 16
// baseline (106.985 us; speedup 1.0000x reference)
//
#include <hip/hip_runtime.h>
#include <math.h>

#define BB 16
#define NN 1024
#define FH 64
#define NH 4
#define LOG2E 1.4426950408889634f

typedef __attribute__((ext_vector_type(8))) short short8;
typedef __attribute__((ext_vector_type(4))) float f32x4;
typedef __attribute__((ext_vector_type(4))) unsigned u32x4;
typedef unsigned long long u64;
typedef unsigned short ushort_t;

__device__ inline unsigned f2bf(float x) {
    unsigned u = __builtin_bit_cast(unsigned, x);
    u += 0x7fff + ((u >> 16) & 1);   // round-to-nearest-even
    return u >> 16;
}
__device__ inline unsigned pkbf(float lo, float hi) {
    unsigned r;
    asm("v_cvt_pk_bf16_f32 %0, %1, %2" : "=v"(r) : "v"(lo), "v"(hi));
    return r;
}
__device__ inline float bf2f(short v) {
    return __builtin_bit_cast(float, (unsigned)((unsigned short)v) << 16);
}

// ---------------------------------------------------------------------------
// adj -> bitmask (all blocks) + weight transpose to bf16 (first 320 blocks)
// + zero d_out (block 0; stream-ordered long before mean1's atomics).
// ---------------------------------------------------------------------------
__global__ void pack_kernel(const int* __restrict__ adj, u64* __restrict__ bm,
                            const float* __restrict__ Whd, const float* __restrict__ Wo,
                            ushort_t* __restrict__ BT1, ushort_t* __restrict__ BT2,
                            float* __restrict__ outz) {
    const int row = blockIdx.x * 4 + (threadIdx.x >> 6);
    const int lane = threadIdx.x & 63;
    const int* __restrict__ ar = adj + (size_t)row * NN;
    #pragma unroll
    for (int g = 0; g < 16; ++g) {
        u64 m = __ballot(ar[g * 64 + lane] > 0);
        if (lane == 0) bm[row * 16 + g] = m;
    }
    const int col = blockIdx.x, k = threadIdx.x;
    if (col < 256)      BT1[col * 256 + k] = (ushort_t)f2bf(Whd[(col >> 6) * 16384 + k * 64 + (col & 63)]);
    else if (col < 320) BT2[(col - 256) * 256 + k] = (ushort_t)f2bf(Wo[k * 64 + (col - 256)]);
    if (col == 0) {
        #pragma unroll
        for (int i = 0; i < 4; ++i) outz[i * 256 + k] = 0.f;
    }
}

// ---------------------------------------------------------------------------
// Fused MFMA GEMM + score epilogue + bf16 transposed WhbT output.
// s2 is stored PRE-SCALED by log2e (consumed only by apply).
// ---------------------------------------------------------------------------
template <int A_BF16>
__global__ __launch_bounds__(256, 4) void gemm_fused(
    const void* __restrict__ Ap, const ushort_t* __restrict__ BT,
    const float* __restrict__ av, ushort_t* __restrict__ WhbT,
    float* __restrict__ s1, float* __restrict__ s2, const int S) {
    constexpr int K = 256;
    __shared__ __align__(16) short tbuf[64][72];
    const int tid = threadIdx.x;
    const int w = tid >> 6, l = tid & 63, lo = l & 15, kg = l >> 4;

    const int nx = gridDim.x;
    const int id = blockIdx.y * nx + blockIdx.x;
    const int nwg = nx * gridDim.y;
    const int lid = (id & 7) * (nwg >> 3) + (id >> 3);   // bijective: nwg % 8 == 0
    const int row0 = (lid / nx) * 64, col0 = (lid % nx) * 64;

    const int b = row0 >> 10, j0 = row0 & (NN - 1);
    const int hsel = col0 >> 6;

    f32x4 acc[4];
    #pragma unroll
    for (int cb = 0; cb < 4; ++cb) acc[cb] = (f32x4){0.f, 0.f, 0.f, 0.f};

    if (A_BF16) {
        const ushort_t* __restrict__ arow = (const ushort_t*)Ap + (size_t)(row0 + w * 16 + lo) * K;
        #pragma unroll
        for (int ks = 0; ks < 8; ++ks) {
            const int k0 = ks * 32 + kg * 8;
            const short8 af = *(const short8*)(arow + k0);
            #pragma unroll
            for (int cb = 0; cb < 4; ++cb) {
                const short8 bf = *(const short8*)(BT + (size_t)(col0 + cb * 16 + lo) * K + k0);
                acc[cb] = __builtin_amdgcn_mfma_f32_16x16x32_bf16(af, bf, acc[cb], 0, 0, 0);
            }
        }
    } else {
        const float* __restrict__ arow = (const float*)Ap + (size_t)(row0 + w * 16 + lo) * K;
        #pragma unroll
        for (int ks = 0; ks < 8; ++ks) {
            const int k0 = ks * 32 + kg * 8;
            const float4 a0 = *(const float4*)(arow + k0);
            const float4 a1 = *(const float4*)(arow + k0 + 4);
            u32x4 ap;
            ap[0] = pkbf(a0.x, a0.y); ap[1] = pkbf(a0.z, a0.w);
            ap[2] = pkbf(a1.x, a1.y); ap[3] = pkbf(a1.z, a1.w);
            const short8 af = __builtin_bit_cast(short8, ap);
            #pragma unroll
            for (int cb = 0; cb < 4; ++cb) {
                const short8 bf = *(const short8*)(BT + (size_t)(col0 + cb * 16 + lo) * K + k0);
                acc[cb] = __builtin_amdgcn_mfma_f32_16x16x32_bf16(af, bf, acc[cb], 0, 0, 0);
            }
        }
    }

    float a1v[4], a2v[4];
    #pragma unroll
    for (int cb = 0; cb < 4; ++cb) {
        a1v[cb] = av[hsel * 128 + cb * 16 + lo];
        a2v[cb] = av[hsel * 128 + 64 + cb * 16 + lo];
    }
    float sp1[4], sp2[4];
    #pragma unroll
    for (int r = 0; r < 4; ++r) {
        sp1[r] = acc[0][r] * a1v[0] + acc[1][r] * a1v[1] + acc[2][r] * a1v[2] + acc[3][r] * a1v[3];
        sp2[r] = acc[0][r] * a2v[0] + acc[1][r] * a2v[1] + acc[2][r] * a2v[2] + acc[3][r] * a2v[3];
    }
    #pragma unroll
    for (int m = 1; m < 16; m <<= 1) {
        #pragma unroll
        for (int r = 0; r < 4; ++r) {
            sp1[r] += __shfl_xor(sp1[r], m);
            sp2[r] += __shfl_xor(sp2[r], m);
        }
    }
    if (lo == 0) {
        #pragma unroll
        for (int r = 0; r < 4; ++r) {
            const int R = row0 + w * 16 + kg * 4 + r;
            s1[hsel * (BB * NN) + R] = sp1[r];
            s2[hsel * (BB * NN) + R] = sp2[r] * LOG2E;
        }
    }

    #pragma unroll
    for (int cb = 0; cb < 4; ++cb)
        #pragma unroll
        for (int rp = 0; rp < 2; ++rp)
            ((unsigned*)tbuf)[(cb * 16 + lo) * 36 + w * 8 + kg * 2 + rp] =
                pkbf(acc[cb][rp * 2], acc[cb][rp * 2 + 1]);
    __syncthreads();
    const int fl = tid >> 2, ch = tid & 3;
    const short8 v0 = *(const short8*)((const short*)tbuf + fl * 72 + ch * 16);
    const short8 v1 = *(const short8*)((const short*)tbuf + fl * 72 + ch * 16 + 8);
    ushort_t* dst = WhbT + ((size_t)(b * S) + col0 + fl) * NN + j0 + ch * 16;
    *(short8*)dst = v0;
    *(short8*)(dst + 8) = v1;
}

// ---------------------------------------------------------------------------
// Fused attention apply, stats-free (unnormalized P + MFMA-ones row sums).
// s2 arrives pre-scaled by log2e. P packed via v_cvt_pk_bf16_f32.
// OUT_BF16=1 (JQ=1): normalize in epilogue, write hcat bf16.
// OUT_BF16=0 (JQ>1): write bf16 raw partials + f32 per-quarter row sums.
// Wh^T chunks double-buffered in LDS, 1 barrier/chunk, prefetch depth 2.
// ---------------------------------------------------------------------------
template <int H, int JQ, int OUT_BF16>
__global__ __launch_bounds__(256, 4) void apply_kernel(
    const ushort_t* __restrict__ WhbT, const int S,
    const float* __restrict__ s1, const float* __restrict__ s2,
    const unsigned* __restrict__ bm32,
    void* __restrict__ outp, float* __restrict__ sums) {
    constexpr int JLEN = NN / JQ;
    constexpr int BW = JLEN / 32;
    constexpr int NCH = JLEN / 64;
    constexpr int NB = 16 * 16 * H * JQ;           // total blocks
    constexpr int SB = 2 * 8192;
    constexpr int UBUF = SB;                       // obuf [64][72] bf16 = 9216 < SB

    __shared__ __align__(16) float s2s[JLEN];
    __shared__ unsigned bs[64][BW + 1];
    __shared__ __align__(16) char ubuf[UBUF];
    auto stage = (unsigned (*)[64][32])ubuf;       // [2][64 f-rows][8 slots x 4 u32]

    const int Bk = blockIdx.x;
    const int lid = (Bk & 7) * (NB / 8) + (Bk >> 3);   // XCD-contiguous, bijective
    const int it = lid & 15;
    const int b  = (lid >> 4) & 15;
    const int z  = lid >> 8;
    const int h  = (H > 1) ? z : 0;
    const int jq = (JQ > 1) ? z : 0;
    const int j0g = jq * JLEN;

    const int tid = threadIdx.x;
    const int w = tid >> 6, l = tid & 63;
    const int lo = l & 15, kg = l >> 4;
    const int iloc = w * 16 + lo;
    const int rbase = b * NN + it * 64;
    const int gi = rbase + iloc;
    const int hb = h * (BB * NN);

    const ushort_t* __restrict__ whb = WhbT + ((size_t)(b * S + h * FH)) * NN + j0g;

    const int r0 = tid >> 3, st = tid & 7;
    const int sw = (st ^ (r0 & 7)) * 4;
    const size_t ga = (size_t)r0 * NN + st * 8;
    const size_t gb = (size_t)(r0 + 32) * NN + st * 8;

    // prologue: chunk-0 loads (hidden under s2/bits staging)
    int4 cva0 = *(const int4*)(whb + ga);
    int4 cva1 = *(const int4*)(whb + gb);

    // stage s2 (already log2e-scaled) + adjacency bits
    const float* __restrict__ s2g = s2 + hb + b * NN + j0g;
    for (int k = tid; k < JLEN / 4; k += 256)
        *(float4*)(s2s + k * 4) = *(const float4*)(s2g + k * 4);
    for (int idx = tid; idx < 64 * BW; idx += 256) {
        int r = idx / BW, wd = idx - r * BW;
        bs[r][wd] = bm32[(size_t)(rbase + r) * 32 + (j0g >> 5) + wd];
    }

    const float s1L = s1[hb + gi] * LOG2E;
    const float Arow = s1L;
    const float Brow = s1L * 0.2f;

    short8 ones;
    #pragma unroll
    for (int e = 0; e < 8; ++e) ones[e] = (short)0x3F80;   // bf16 1.0

    f32x4 acc[4];
    #pragma unroll
    for (int fb = 0; fb < 4; ++fb) acc[fb] = (f32x4){0.f, 0.f, 0.f, 0.f};
    f32x4 accs = (f32x4){0.f, 0.f, 0.f, 0.f};

    // write chunk 0 into buf 0; reload cva with chunk 1; single barrier
    *(int4*)&stage[0][r0][sw] = cva0;
    *(int4*)&stage[0][r0 + 32][sw] = cva1;
    if (1 < NCH) {
        cva0 = *(const int4*)(whb + 64 + ga);
        cva1 = *(const int4*)(whb + 64 + gb);
    }
    __syncthreads();

    #pragma unroll
    for (int c = 0; c < NCH; ++c) {
        int4 cvb0, cvb1;
        if (c + 2 < NCH) {                          // issue chunk c+2 loads
            const ushort_t* src = whb + (c + 2) * 64;
            cvb0 = *(const int4*)(src + ga);
            cvb1 = *(const int4*)(src + gb);
        }
        #pragma unroll
        for (int ks = 0; ks < 2; ++ks) {
            const int kb = c * 64 + ks * 32 + kg * 8;
            const unsigned byte = (bs[iloc][c * 2 + ks] >> (kg * 8)) & 0xFF;
            const float4 sa = *(const float4*)(s2s + kb);
            const float4 sb = *(const float4*)(s2s + kb + 4);
            const float s2r[8] = {sa.x, sa.y, sa.z, sa.w, sb.x, sb.y, sb.z, sb.w};
            float pv[8];
            #pragma unroll
            for (int e = 0; e < 8; ++e) {
                const float t = s2r[e];
                const float u = Arow + t;
                const float v = __builtin_fmaf(t, 0.2f, Brow);
                float ev = fmaxf(u, v);
                ev = ((byte >> e) & 1) ? ev : -1.0e5f;
                pv[e] = __builtin_amdgcn_exp2f(ev);
            }
            u32x4 pk;
            pk[0] = pkbf(pv[0], pv[1]); pk[1] = pkbf(pv[2], pv[3]);
            pk[2] = pkbf(pv[4], pv[5]); pk[3] = pkbf(pv[6], pv[7]);
            const short8 bfr = __builtin_bit_cast(short8, pk);
            __builtin_amdgcn_s_setprio(1);
            #pragma unroll
            for (int fb = 0; fb < 4; ++fb) {
                const int row = fb * 16 + lo;
                const int slot = (ks * 4 + kg) ^ (row & 7);
                const short8 afr = *(const short8*)&stage[c & 1][row][slot * 4];
                acc[fb] = __builtin_amdgcn_mfma_f32_16x16x32_bf16(afr, bfr, acc[fb], 0, 0, 0);
            }
            accs = __builtin_amdgcn_mfma_f32_16x16x32_bf16(ones, bfr, accs, 0, 0, 0);
            __builtin_amdgcn_s_setprio(0);
        }
        if (c + 1 < NCH) {                          // write landed chunk c+1
            *(int4*)&stage[(c + 1) & 1][r0][sw] = cva0;
            *(int4*)&stage[(c + 1) & 1][r0 + 32][sw] = cva1;
        }
        cva0 = cvb0;
        cva1 = cvb1;
        __syncthreads();
    }

    // accs[r] = sum_j P[i=iloc][j] over this block's j-range (all r, all kg)
    // lane (lo,kg) holds i = iloc, f = fb*16 + kg*4 + r
    const float inv = OUT_BF16 ? (1.0f / accs[0]) : 1.0f;
    if (!OUT_BF16 && kg == 0)
        sums[(size_t)jq * (BB * NN) + rbase + iloc] = accs[0];

    unsigned* ot = (unsigned*)ubuf;                // [64][36] u32 view of [64][72] bf16
    #pragma unroll
    for (int fb = 0; fb < 4; ++fb)
        #pragma unroll
        for (int rp = 0; rp < 2; ++rp)
            ot[iloc * 36 + fb * 8 + kg * 2 + rp] =
                pkbf(acc[fb][rp * 2] * inv, acc[fb][rp * 2 + 1] * inv);
    __syncthreads();
    const int i2 = tid >> 2, ch = tid & 3;
    const short8 v0 = *(const short8*)((const short*)ubuf + i2 * 72 + ch * 16);
    const short8 v1 = *(const short8*)((const short*)ubuf + i2 * 72 + ch * 16 + 8);
    if constexpr (OUT_BF16) {
        ushort_t* dst = (ushort_t*)outp + (size_t)(b * NN + it * 64 + i2) * 256 + h * FH + ch * 16;
        *(short8*)dst = v0;
        *(short8*)(dst + 8) = v1;
    } else {
        ushort_t* dst = (ushort_t*)outp + (size_t)jq * (BB * NN * FH)
                      + (size_t)(b * NN + it * 64 + i2) * FH + ch * 16;
        *(short8*)dst = v0;
        *(short8*)(dst + 8) = v1;
    }
}

// ---------------------------------------------------------------------------
// Mean: combine 8 bf16 j-partials, normalize by summed row-sums, ELU,
// partial mean, atomicAdd into (pack-zeroed) out. Grid (16 b, 16 chunks).
// ---------------------------------------------------------------------------
__global__ __launch_bounds__(256) void mean1_kernel(const ushort_t* __restrict__ part,
                                                    const float* __restrict__ sums,
                                                    float* __restrict__ out) {
    const int b = blockIdx.x, ck = blockIdx.y;
    const int tid = threadIdx.x;
    const int f = tid & 63, g = tid >> 6;
    float acc = 0.f;
    #pragma unroll
    for (int i = g; i < 64; i += 4) {
        const int row = b * NN + ck * 64 + i;
        float s = 0.f;
        #pragma unroll
        for (int q = 0; q < 8; ++q) s += sums[(size_t)q * 16384 + row];
        float v = 0.f;
        #pragma unroll
        for (int q = 0; q < 8; ++q)
            v += bf2f((short)part[(size_t)q * 1048576 + (size_t)row * FH + f]);
        v /= s;
        v = (v > 0.f) ? v : (__builtin_amdgcn_exp2f(v * LOG2E) - 1.0f);
        acc += v;
    }
    __shared__ float r[4][64];
    r[g][f] = acc;
    __syncthreads();
    if (g == 0)
        atomicAdd(&out[b * FH + f],
                  (r[0][f] + r[1][f] + r[2][f] + r[3][f]) * (1.0f / NN));
}

extern "C" void kernel_launch(void* const* d_in, const int* in_sizes, int n_in,
                              void* d_out, int out_size, void* d_ws, size_t ws_size,
                              hipStream_t stream) {
    const float* x       = (const float*)d_in[0];
    const int*   adj     = (const int*)d_in[1];
    const float* W_heads = (const float*)d_in[2];
    const float* a_heads = (const float*)d_in[3];
    const float* W_out   = (const float*)d_in[4];
    const float* a_out   = (const float*)d_in[5];
    float* out = (float*)d_out;
    float* f0  = (float*)d_ws;

    // workspace (float offsets).
    // hcat [16384][256] bf16 (8MB) at f0; WhbT1 (8MB) at +8MB.
    // part2 [8][16384][64] bf16 (16MB) overlays both (dead when apply2 runs).
    ushort_t* hcat  = (ushort_t*)f0;                     // 8 MB
    ushort_t* part2 = (ushort_t*)f0;                     // 16 MB (after gemm2)
    ushort_t* WhbT1 = (ushort_t*)(f0 + 2097152);         // [16][256][1024] bf16, 8 MB
    ushort_t* WhbT2 = (ushort_t*)(f0 + 4194304);         // [16][64][1024] bf16, 2 MB
    u64*      bmask = (u64*)(f0 + 4718592);              // [16384][16] u64, 2 MB
    ushort_t* WbT1  = (ushort_t*)(f0 + 5242880);         // [256][256] bf16
    ushort_t* WbT2  = (ushort_t*)(f0 + 5275648);         // [64][256] bf16
    float*    s1_1  = f0 + 5283840;                      // [4][16384]
    float*    s2_1  = s1_1 + 65536;
    float*    s1_2  = s2_1 + 65536;                      // [16384]
    float*    s2_2  = s1_2 + 16384;
    float*    sums2 = s2_2 + 16384;                      // [8][16384]

    dim3 blk(256);

    // shared pre-pass (adj bitmask + weight transpose + out zeroing)
    pack_kernel<<<dim3(BB * NN / 4), blk, 0, stream>>>(adj, bmask, W_heads, W_out,
                                                       WbT1, WbT2, out);

    // layer 1 (softmax normalization fused into apply via MFMA row-sums)
    gemm_fused<0><<<dim3(4, 256), blk, 0, stream>>>(x, WbT1, a_heads, WhbT1, s1_1, s2_1, 256);
    apply_kernel<NH, 1, 1><<<dim3(1024), blk, 0, stream>>>(WhbT1, 256, s1_1, s2_1,
                                                           (const unsigned*)bmask, hcat, nullptr);

    // layer 2
    gemm_fused<1><<<dim3(1, 256), blk, 0, stream>>>(hcat, WbT2, a_out, WhbT2, s1_2, s2_2, 64);
    apply_kernel<1, 8, 0><<<dim3(2048), blk, 0, stream>>>(WhbT2, 64, s1_2, s2_2,
                                                          (const unsigned*)bmask, part2, sums2);

    // combine partials + normalize + elu + mean (atomic tail; out zeroed in pack)
    mean1_kernel<<<dim3(BB, 16), blk, 0, stream>>>(part2, sums2, out);
}

// Round 17
// 94.249 us; speedup vs baseline: 1.1351x; 1.1351x over previous
//
#include <hip/hip_runtime.h>
#include <math.h>

#define BB 16
#define NN 1024
#define FH 64
#define NH 4
#define LOG2E 1.4426950408889634f

typedef __attribute__((ext_vector_type(8))) short short8;
typedef __attribute__((ext_vector_type(4))) float f32x4;
typedef __attribute__((ext_vector_type(4))) unsigned u32x4;
typedef unsigned long long u64;
typedef unsigned short ushort_t;

__device__ inline unsigned f2bf(float x) {
    unsigned u = __builtin_bit_cast(unsigned, x);
    u += 0x7fff + ((u >> 16) & 1);   // round-to-nearest-even
    return u >> 16;
}
__device__ inline unsigned pkbf(float lo, float hi) {
    unsigned r;
    asm("v_cvt_pk_bf16_f32 %0, %1, %2" : "=v"(r) : "v"(lo), "v"(hi));
    return r;
}
__device__ inline float bf2f(short v) {
    return __builtin_bit_cast(float, (unsigned)((unsigned short)v) << 16);
}

// ---------------------------------------------------------------------------
// adj -> bitmask (all blocks) + weight transpose to bf16 (first 320 blocks)
// + zero d_out (block 0; stream-ordered long before mean1's atomics).
// ---------------------------------------------------------------------------
__global__ void pack_kernel(const int* __restrict__ adj, u64* __restrict__ bm,
                            const float* __restrict__ Whd, const float* __restrict__ Wo,
                            ushort_t* __restrict__ BT1, ushort_t* __restrict__ BT2,
                            float* __restrict__ outz) {
    const int row = blockIdx.x * 4 + (threadIdx.x >> 6);
    const int lane = threadIdx.x & 63;
    const int* __restrict__ ar = adj + (size_t)row * NN;
    #pragma unroll
    for (int g = 0; g < 16; ++g) {
        u64 m = __ballot(ar[g * 64 + lane] > 0);
        if (lane == 0) bm[row * 16 + g] = m;
    }
    const int col = blockIdx.x, k = threadIdx.x;
    if (col < 256)      BT1[col * 256 + k] = (ushort_t)f2bf(Whd[(col >> 6) * 16384 + k * 64 + (col & 63)]);
    else if (col < 320) BT2[(col - 256) * 256 + k] = (ushort_t)f2bf(Wo[k * 64 + (col - 256)]);
    if (col == 0) {
        #pragma unroll
        for (int i = 0; i < 4; ++i) outz[i * 256 + k] = 0.f;
    }
}

// ---------------------------------------------------------------------------
// Fused MFMA GEMM + score epilogue + bf16 transposed WhbT output.
// s2 is stored PRE-SCALED by log2e (consumed only by apply).
// ---------------------------------------------------------------------------
template <int A_BF16>
__global__ __launch_bounds__(256, 4) void gemm_fused(
    const void* __restrict__ Ap, const ushort_t* __restrict__ BT,
    const float* __restrict__ av, ushort_t* __restrict__ WhbT,
    float* __restrict__ s1, float* __restrict__ s2, const int S) {
    constexpr int K = 256;
    __shared__ __align__(16) short tbuf[64][72];
    const int tid = threadIdx.x;
    const int w = tid >> 6, l = tid & 63, lo = l & 15, kg = l >> 4;

    const int nx = gridDim.x;
    const int id = blockIdx.y * nx + blockIdx.x;
    const int nwg = nx * gridDim.y;
    const int lid = (id & 7) * (nwg >> 3) + (id >> 3);   // bijective: nwg % 8 == 0
    const int row0 = (lid / nx) * 64, col0 = (lid % nx) * 64;

    const int b = row0 >> 10, j0 = row0 & (NN - 1);
    const int hsel = col0 >> 6;

    f32x4 acc[4];
    #pragma unroll
    for (int cb = 0; cb < 4; ++cb) acc[cb] = (f32x4){0.f, 0.f, 0.f, 0.f};

    if (A_BF16) {
        const ushort_t* __restrict__ arow = (const ushort_t*)Ap + (size_t)(row0 + w * 16 + lo) * K;
        #pragma unroll
        for (int ks = 0; ks < 8; ++ks) {
            const int k0 = ks * 32 + kg * 8;
            const short8 af = *(const short8*)(arow + k0);
            #pragma unroll
            for (int cb = 0; cb < 4; ++cb) {
                const short8 bf = *(const short8*)(BT + (size_t)(col0 + cb * 16 + lo) * K + k0);
                acc[cb] = __builtin_amdgcn_mfma_f32_16x16x32_bf16(af, bf, acc[cb], 0, 0, 0);
            }
        }
    } else {
        const float* __restrict__ arow = (const float*)Ap + (size_t)(row0 + w * 16 + lo) * K;
        #pragma unroll
        for (int ks = 0; ks < 8; ++ks) {
            const int k0 = ks * 32 + kg * 8;
            const float4 a0 = *(const float4*)(arow + k0);
            const float4 a1 = *(const float4*)(arow + k0 + 4);
            u32x4 ap;
            ap[0] = pkbf(a0.x, a0.y); ap[1] = pkbf(a0.z, a0.w);
            ap[2] = pkbf(a1.x, a1.y); ap[3] = pkbf(a1.z, a1.w);
            const short8 af = __builtin_bit_cast(short8, ap);
            #pragma unroll
            for (int cb = 0; cb < 4; ++cb) {
                const short8 bf = *(const short8*)(BT + (size_t)(col0 + cb * 16 + lo) * K + k0);
                acc[cb] = __builtin_amdgcn_mfma_f32_16x16x32_bf16(af, bf, acc[cb], 0, 0, 0);
            }
        }
    }

    float a1v[4], a2v[4];
    #pragma unroll
    for (int cb = 0; cb < 4; ++cb) {
        a1v[cb] = av[hsel * 128 + cb * 16 + lo];
        a2v[cb] = av[hsel * 128 + 64 + cb * 16 + lo];
    }
    float sp1[4], sp2[4];
    #pragma unroll
    for (int r = 0; r < 4; ++r) {
        sp1[r] = acc[0][r] * a1v[0] + acc[1][r] * a1v[1] + acc[2][r] * a1v[2] + acc[3][r] * a1v[3];
        sp2[r] = acc[0][r] * a2v[0] + acc[1][r] * a2v[1] + acc[2][r] * a2v[2] + acc[3][r] * a2v[3];
    }
    #pragma unroll
    for (int m = 1; m < 16; m <<= 1) {
        #pragma unroll
        for (int r = 0; r < 4; ++r) {
            sp1[r] += __shfl_xor(sp1[r], m);
            sp2[r] += __shfl_xor(sp2[r], m);
        }
    }
    if (lo == 0) {
        #pragma unroll
        for (int r = 0; r < 4; ++r) {
            const int R = row0 + w * 16 + kg * 4 + r;
            s1[hsel * (BB * NN) + R] = sp1[r];
            s2[hsel * (BB * NN) + R] = sp2[r] * LOG2E;
        }
    }

    #pragma unroll
    for (int cb = 0; cb < 4; ++cb)
        #pragma unroll
        for (int rp = 0; rp < 2; ++rp)
            ((unsigned*)tbuf)[(cb * 16 + lo) * 36 + w * 8 + kg * 2 + rp] =
                pkbf(acc[cb][rp * 2], acc[cb][rp * 2 + 1]);
    __syncthreads();
    const int fl = tid >> 2, ch = tid & 3;
    const short8 v0 = *(const short8*)((const short*)tbuf + fl * 72 + ch * 16);
    const short8 v1 = *(const short8*)((const short*)tbuf + fl * 72 + ch * 16 + 8);
    ushort_t* dst = WhbT + ((size_t)(b * S) + col0 + fl) * NN + j0 + ch * 16;
    *(short8*)dst = v0;
    *(short8*)(dst + 8) = v1;
}

// ---------------------------------------------------------------------------
// Fused attention apply, stats-free (unnormalized P + MFMA-ones row sums).
// s2 arrives pre-scaled by log2e. P packed via v_cvt_pk_bf16_f32.
// OUT_BF16=1 (JQ=1): normalize in epilogue, write hcat bf16.
// OUT_BF16=0 (JQ=4): write bf16 raw partials + f32 per-quarter row sums.
// Wh^T chunks double-buffered in LDS, 1 barrier/chunk, prefetch depth 2.
// ---------------------------------------------------------------------------
template <int H, int JQ, int OUT_BF16>
__global__ __launch_bounds__(256, 4) void apply_kernel(
    const ushort_t* __restrict__ WhbT, const int S,
    const float* __restrict__ s1, const float* __restrict__ s2,
    const unsigned* __restrict__ bm32,
    void* __restrict__ outp, float* __restrict__ sums) {
    constexpr int JLEN = NN / JQ;
    constexpr int BW = JLEN / 32;
    constexpr int NCH = JLEN / 64;
    constexpr int SB = 2 * 8192;
    constexpr int UBUF = SB;                       // obuf [64][72] bf16 = 9216 < SB

    __shared__ __align__(16) float s2s[JLEN];
    __shared__ unsigned bs[64][BW + 1];
    __shared__ __align__(16) char ubuf[UBUF];
    auto stage = (unsigned (*)[64][32])ubuf;       // [2][64 f-rows][8 slots x 4 u32]

    const int Bk = blockIdx.x;
    const int lid = (Bk & 7) * 128 + (Bk >> 3);    // XCD-contiguous logical id
    const int it = lid & 15;
    const int b  = (lid >> 4) & 15;
    const int z  = lid >> 8;
    const int h  = (H > 1) ? z : 0;
    const int jq = (JQ > 1) ? z : 0;
    const int j0g = jq * JLEN;

    const int tid = threadIdx.x;
    const int w = tid >> 6, l = tid & 63;
    const int lo = l & 15, kg = l >> 4;
    const int iloc = w * 16 + lo;
    const int rbase = b * NN + it * 64;
    const int gi = rbase + iloc;
    const int hb = h * (BB * NN);

    const ushort_t* __restrict__ whb = WhbT + ((size_t)(b * S + h * FH)) * NN + j0g;

    const int r0 = tid >> 3, st = tid & 7;
    const int sw = (st ^ (r0 & 7)) * 4;
    const size_t ga = (size_t)r0 * NN + st * 8;
    const size_t gb = (size_t)(r0 + 32) * NN + st * 8;

    // prologue: chunk-0 loads (hidden under s2/bits staging)
    int4 cva0 = *(const int4*)(whb + ga);
    int4 cva1 = *(const int4*)(whb + gb);

    // stage s2 (already log2e-scaled) + adjacency bits
    const float* __restrict__ s2g = s2 + hb + b * NN + j0g;
    for (int k = tid; k < JLEN / 4; k += 256)
        *(float4*)(s2s + k * 4) = *(const float4*)(s2g + k * 4);
    for (int idx = tid; idx < 64 * BW; idx += 256) {
        int r = idx / BW, wd = idx - r * BW;
        bs[r][wd] = bm32[(size_t)(rbase + r) * 32 + (j0g >> 5) + wd];
    }

    const float s1L = s1[hb + gi] * LOG2E;
    const float Arow = s1L;
    const float Brow = s1L * 0.2f;

    short8 ones;
    #pragma unroll
    for (int e = 0; e < 8; ++e) ones[e] = (short)0x3F80;   // bf16 1.0

    f32x4 acc[4];
    #pragma unroll
    for (int fb = 0; fb < 4; ++fb) acc[fb] = (f32x4){0.f, 0.f, 0.f, 0.f};
    f32x4 accs = (f32x4){0.f, 0.f, 0.f, 0.f};

    // write chunk 0 into buf 0; reload cva with chunk 1; single barrier
    *(int4*)&stage[0][r0][sw] = cva0;
    *(int4*)&stage[0][r0 + 32][sw] = cva1;
    if (1 < NCH) {
        cva0 = *(const int4*)(whb + 64 + ga);
        cva1 = *(const int4*)(whb + 64 + gb);
    }
    __syncthreads();

    #pragma unroll
    for (int c = 0; c < NCH; ++c) {
        int4 cvb0, cvb1;
        if (c + 2 < NCH) {                          // issue chunk c+2 loads
            const ushort_t* src = whb + (c + 2) * 64;
            cvb0 = *(const int4*)(src + ga);
            cvb1 = *(const int4*)(src + gb);
        }
        #pragma unroll
        for (int ks = 0; ks < 2; ++ks) {
            const int kb = c * 64 + ks * 32 + kg * 8;
            const unsigned byte = (bs[iloc][c * 2 + ks] >> (kg * 8)) & 0xFF;
            const float4 sa = *(const float4*)(s2s + kb);
            const float4 sb = *(const float4*)(s2s + kb + 4);
            const float s2r[8] = {sa.x, sa.y, sa.z, sa.w, sb.x, sb.y, sb.z, sb.w};
            float pv[8];
            #pragma unroll
            for (int e = 0; e < 8; ++e) {
                const float t = s2r[e];
                const float u = Arow + t;
                const float v = __builtin_fmaf(t, 0.2f, Brow);
                float ev = fmaxf(u, v);
                ev = ((byte >> e) & 1) ? ev : -1.0e5f;
                pv[e] = __builtin_amdgcn_exp2f(ev);
            }
            u32x4 pk;
            pk[0] = pkbf(pv[0], pv[1]); pk[1] = pkbf(pv[2], pv[3]);
            pk[2] = pkbf(pv[4], pv[5]); pk[3] = pkbf(pv[6], pv[7]);
            const short8 bfr = __builtin_bit_cast(short8, pk);
            __builtin_amdgcn_s_setprio(1);
            #pragma unroll
            for (int fb = 0; fb < 4; ++fb) {
                const int row = fb * 16 + lo;
                const int slot = (ks * 4 + kg) ^ (row & 7);
                const short8 afr = *(const short8*)&stage[c & 1][row][slot * 4];
                acc[fb] = __builtin_amdgcn_mfma_f32_16x16x32_bf16(afr, bfr, acc[fb], 0, 0, 0);
            }
            accs = __builtin_amdgcn_mfma_f32_16x16x32_bf16(ones, bfr, accs, 0, 0, 0);
            __builtin_amdgcn_s_setprio(0);
        }
        if (c + 1 < NCH) {                          // write landed chunk c+1
            *(int4*)&stage[(c + 1) & 1][r0][sw] = cva0;
            *(int4*)&stage[(c + 1) & 1][r0 + 32][sw] = cva1;
        }
        cva0 = cvb0;
        cva1 = cvb1;
        __syncthreads();
    }

    // accs[r] = sum_j P[i=iloc][j] over this block's j-range (all r, all kg)
    // lane (lo,kg) holds i = iloc, f = fb*16 + kg*4 + r
    const float inv = OUT_BF16 ? (1.0f / accs[0]) : 1.0f;
    if (!OUT_BF16 && kg == 0)
        sums[(size_t)jq * (BB * NN) + rbase + iloc] = accs[0];

    unsigned* ot = (unsigned*)ubuf;                // [64][36] u32 view of [64][72] bf16
    #pragma unroll
    for (int fb = 0; fb < 4; ++fb)
        #pragma unroll
        for (int rp = 0; rp < 2; ++rp)
            ot[iloc * 36 + fb * 8 + kg * 2 + rp] =
                pkbf(acc[fb][rp * 2] * inv, acc[fb][rp * 2 + 1] * inv);
    __syncthreads();
    const int i2 = tid >> 2, ch = tid & 3;
    const short8 v0 = *(const short8*)((const short*)ubuf + i2 * 72 + ch * 16);
    const short8 v1 = *(const short8*)((const short*)ubuf + i2 * 72 + ch * 16 + 8);
    if constexpr (OUT_BF16) {
        ushort_t* dst = (ushort_t*)outp + (size_t)(b * NN + it * 64 + i2) * 256 + h * FH + ch * 16;
        *(short8*)dst = v0;
        *(short8*)(dst + 8) = v1;
    } else {
        ushort_t* dst = (ushort_t*)outp + (size_t)jq * (BB * NN * FH)
                      + (size_t)(b * NN + it * 64 + i2) * FH + ch * 16;
        *(short8*)dst = v0;
        *(short8*)(dst + 8) = v1;
    }
}

// ---------------------------------------------------------------------------
// Mean: combine 4 bf16 j-partials, normalize by summed row-sums, ELU,
// partial mean, atomicAdd into (pack-zeroed) out. Grid (16 b, 16 chunks).
// ---------------------------------------------------------------------------
__global__ __launch_bounds__(256) void mean1_kernel(const ushort_t* __restrict__ part,
                                                    const float* __restrict__ sums,
                                                    float* __restrict__ out) {
    const int b = blockIdx.x, ck = blockIdx.y;
    const int tid = threadIdx.x;
    const int f = tid & 63, g = tid >> 6;
    float acc = 0.f;
    #pragma unroll
    for (int i = g; i < 64; i += 4) {
        const int row = b * NN + ck * 64 + i;
        const float srow = sums[row] + sums[row + 16384]
                         + sums[row + 32768] + sums[row + 49152];
        float v = 0.f;
        #pragma unroll
        for (int q = 0; q < 4; ++q)
            v += bf2f((short)part[(size_t)q * 1048576 + (size_t)row * FH + f]);
        v /= srow;
        v = (v > 0.f) ? v : (__builtin_amdgcn_exp2f(v * LOG2E) - 1.0f);
        acc += v;
    }
    __shared__ float r[4][64];
    r[g][f] = acc;
    __syncthreads();
    if (g == 0)
        atomicAdd(&out[b * FH + f],
                  (r[0][f] + r[1][f] + r[2][f] + r[3][f]) * (1.0f / NN));
}

extern "C" void kernel_launch(void* const* d_in, const int* in_sizes, int n_in,
                              void* d_out, int out_size, void* d_ws, size_t ws_size,
                              hipStream_t stream) {
    const float* x       = (const float*)d_in[0];
    const int*   adj     = (const int*)d_in[1];
    const float* W_heads = (const float*)d_in[2];
    const float* a_heads = (const float*)d_in[3];
    const float* W_out   = (const float*)d_in[4];
    const float* a_out   = (const float*)d_in[5];
    float* out = (float*)d_out;
    float* f0  = (float*)d_ws;

    // workspace (float offsets). part (bf16, 8MB) overlays hcat (dead after gemm2).
    ushort_t* hcat  = (ushort_t*)f0;                     // [16384][256] bf16, 8 MB
    ushort_t* part  = (ushort_t*)f0;                     // [4][16384][64] bf16, 8 MB
    ushort_t* WhbT1 = (ushort_t*)(f0 + 2097152);         // [16][256][1024] bf16, 8 MB
    ushort_t* WhbT2 = (ushort_t*)(f0 + 4194304);         // [16][64][1024] bf16, 2 MB
    u64*      bmask = (u64*)(f0 + 4718592);              // [16384][16] u64, 2 MB
    ushort_t* WbT1  = (ushort_t*)(f0 + 5242880);         // [256][256] bf16
    ushort_t* WbT2  = (ushort_t*)(f0 + 5275648);         // [64][256] bf16
    float*    s1_1  = f0 + 5283840;                      // [4][16384]
    float*    s2_1  = s1_1 + 65536;
    float*    s1_2  = s2_1 + 65536;                      // [16384]
    float*    s2_2  = s1_2 + 16384;
    float*    sums2 = s2_2 + 16384;                      // [4][16384]

    dim3 blk(256);

    // shared pre-pass (adj bitmask + weight transpose + out zeroing)
    pack_kernel<<<dim3(BB * NN / 4), blk, 0, stream>>>(adj, bmask, W_heads, W_out,
                                                       WbT1, WbT2, out);

    // layer 1 (softmax normalization fused into apply via MFMA row-sums)
    gemm_fused<0><<<dim3(4, 256), blk, 0, stream>>>(x, WbT1, a_heads, WhbT1, s1_1, s2_1, 256);
    apply_kernel<NH, 1, 1><<<dim3(1024), blk, 0, stream>>>(WhbT1, 256, s1_1, s2_1,
                                                           (const unsigned*)bmask, hcat, nullptr);

    // layer 2
    gemm_fused<1><<<dim3(1, 256), blk, 0, stream>>>(hcat, WbT2, a_out, WhbT2, s1_2, s2_2, 64);
    apply_kernel<1, 4, 0><<<dim3(1024), blk, 0, stream>>>(WhbT2, 64, s1_2, s2_2,
                                                          (const unsigned*)bmask, part, sums2);

    // combine partials + normalize + elu + mean (atomic tail; out zeroed in pack)
    mean1_kernel<<<dim3(BB, 16), blk, 0, stream>>>(part, sums2, out);
}

// Round 19
// 93.858 us; speedup vs baseline: 1.1399x; 1.0042x over previous
//
#include <hip/hip_runtime.h>
#include <math.h>

#define BB 16
#define NN 1024
#define FH 64
#define NH 4
#define LOG2E 1.4426950408889634f

typedef __attribute__((ext_vector_type(8))) short short8;
typedef __attribute__((ext_vector_type(4))) float f32x4;
typedef __attribute__((ext_vector_type(4))) unsigned u32x4;
typedef unsigned long long u64;
typedef unsigned short ushort_t;

__device__ inline unsigned f2bf(float x) {
    unsigned u = __builtin_bit_cast(unsigned, x);
    u += 0x7fff + ((u >> 16) & 1);   // round-to-nearest-even
    return u >> 16;
}
__device__ inline unsigned pkbf(float lo, float hi) {
    unsigned r;
    asm("v_cvt_pk_bf16_f32 %0, %1, %2" : "=v"(r) : "v"(lo), "v"(hi));
    return r;
}
__device__ inline float bf2f(short v) {
    return __builtin_bit_cast(float, (unsigned)((unsigned short)v) << 16);
}

// ---------------------------------------------------------------------------
// Weight transpose to bf16 (320 blocks) + zero d_out (block 0).
// adj packing moved into gemm1 (overlaps HBM with MFMA).
// ---------------------------------------------------------------------------
__global__ void packw_kernel(const float* __restrict__ Whd, const float* __restrict__ Wo,
                             ushort_t* __restrict__ BT1, ushort_t* __restrict__ BT2,
                             float* __restrict__ outz) {
    const int col = blockIdx.x, k = threadIdx.x;
    if (col < 256)      BT1[col * 256 + k] = (ushort_t)f2bf(Whd[(col >> 6) * 16384 + k * 64 + (col & 63)]);
    else if (col < 320) BT2[(col - 256) * 256 + k] = (ushort_t)f2bf(Wo[k * 64 + (col - 256)]);
    if (col == 0) {
        #pragma unroll
        for (int i = 0; i < 4; ++i) outz[i * 256 + k] = 0.f;
    }
}

// ---------------------------------------------------------------------------
// Fused MFMA GEMM + score epilogue + bf16 transposed WhbT output.
// PACK=1 (layer 1): each block also packs 16 adj rows into the bitmask.
// Even/odd block stagger: odd blocks pack BEFORE the GEMM, even blocks
// AFTER — at any instant ~half the device streams adj (HBM) while the
// other half runs MFMA. bmask's only reader (apply1) is stream-ordered.
// s2 is stored PRE-SCALED by log2e (consumed only by apply).
// ---------------------------------------------------------------------------
template <int A_BF16, int PACK>
__global__ __launch_bounds__(256, 4) void gemm_fused(
    const void* __restrict__ Ap, const ushort_t* __restrict__ BT,
    const float* __restrict__ av, ushort_t* __restrict__ WhbT,
    float* __restrict__ s1, float* __restrict__ s2, const int S,
    const int* __restrict__ adj, u64* __restrict__ bm) {
    constexpr int K = 256;
    __shared__ __align__(16) short tbuf[64][72];
    const int tid = threadIdx.x;
    const int w = tid >> 6, l = tid & 63, lo = l & 15, kg = l >> 4;

    const int nx = gridDim.x;
    const int id = blockIdx.y * nx + blockIdx.x;
    const int nwg = nx * gridDim.y;
    const int lid = (id & 7) * (nwg >> 3) + (id >> 3);   // bijective: nwg % 8 == 0
    const int row0 = (lid / nx) * 64, col0 = (lid % nx) * 64;

    const int b = row0 >> 10, j0 = row0 & (NN - 1);
    const int hsel = col0 >> 6;

    // adjacency packing: 16 rows per block (4 per wave), batched loads + ballots
    auto do_pack = [&]() {
        const int rowb = id * 16 + w * 4;
        const int* __restrict__ ar = adj + (size_t)rowb * NN;
        #pragma unroll
        for (int rr = 0; rr < 4; ++rr) {
            int va[16];
            #pragma unroll
            for (int g = 0; g < 16; ++g) va[g] = ar[(size_t)rr * NN + g * 64 + l];
            #pragma unroll
            for (int g = 0; g < 16; ++g) {
                u64 m = __ballot(va[g] > 0);
                if (l == 0) bm[(rowb + rr) * 16 + g] = m;
            }
        }
    };
    if constexpr (PACK) { if (id & 1) do_pack(); }

    f32x4 acc[4];
    #pragma unroll
    for (int cb = 0; cb < 4; ++cb) acc[cb] = (f32x4){0.f, 0.f, 0.f, 0.f};

    if (A_BF16) {
        const ushort_t* __restrict__ arow = (const ushort_t*)Ap + (size_t)(row0 + w * 16 + lo) * K;
        #pragma unroll
        for (int ks = 0; ks < 8; ++ks) {
            const int k0 = ks * 32 + kg * 8;
            const short8 af = *(const short8*)(arow + k0);
            #pragma unroll
            for (int cb = 0; cb < 4; ++cb) {
                const short8 bf = *(const short8*)(BT + (size_t)(col0 + cb * 16 + lo) * K + k0);
                acc[cb] = __builtin_amdgcn_mfma_f32_16x16x32_bf16(af, bf, acc[cb], 0, 0, 0);
            }
        }
    } else {
        const float* __restrict__ arow = (const float*)Ap + (size_t)(row0 + w * 16 + lo) * K;
        #pragma unroll
        for (int ks = 0; ks < 8; ++ks) {
            const int k0 = ks * 32 + kg * 8;
            const float4 a0 = *(const float4*)(arow + k0);
            const float4 a1 = *(const float4*)(arow + k0 + 4);
            u32x4 ap;
            ap[0] = pkbf(a0.x, a0.y); ap[1] = pkbf(a0.z, a0.w);
            ap[2] = pkbf(a1.x, a1.y); ap[3] = pkbf(a1.z, a1.w);
            const short8 af = __builtin_bit_cast(short8, ap);
            #pragma unroll
            for (int cb = 0; cb < 4; ++cb) {
                const short8 bf = *(const short8*)(BT + (size_t)(col0 + cb * 16 + lo) * K + k0);
                acc[cb] = __builtin_amdgcn_mfma_f32_16x16x32_bf16(af, bf, acc[cb], 0, 0, 0);
            }
        }
    }

    float a1v[4], a2v[4];
    #pragma unroll
    for (int cb = 0; cb < 4; ++cb) {
        a1v[cb] = av[hsel * 128 + cb * 16 + lo];
        a2v[cb] = av[hsel * 128 + 64 + cb * 16 + lo];
    }
    float sp1[4], sp2[4];
    #pragma unroll
    for (int r = 0; r < 4; ++r) {
        sp1[r] = acc[0][r] * a1v[0] + acc[1][r] * a1v[1] + acc[2][r] * a1v[2] + acc[3][r] * a1v[3];
        sp2[r] = acc[0][r] * a2v[0] + acc[1][r] * a2v[1] + acc[2][r] * a2v[2] + acc[3][r] * a2v[3];
    }
    #pragma unroll
    for (int m = 1; m < 16; m <<= 1) {
        #pragma unroll
        for (int r = 0; r < 4; ++r) {
            sp1[r] += __shfl_xor(sp1[r], m);
            sp2[r] += __shfl_xor(sp2[r], m);
        }
    }
    if (lo == 0) {
        #pragma unroll
        for (int r = 0; r < 4; ++r) {
            const int R = row0 + w * 16 + kg * 4 + r;
            s1[hsel * (BB * NN) + R] = sp1[r];
            s2[hsel * (BB * NN) + R] = sp2[r] * LOG2E;
        }
    }

    #pragma unroll
    for (int cb = 0; cb < 4; ++cb)
        #pragma unroll
        for (int rp = 0; rp < 2; ++rp)
            ((unsigned*)tbuf)[(cb * 16 + lo) * 36 + w * 8 + kg * 2 + rp] =
                pkbf(acc[cb][rp * 2], acc[cb][rp * 2 + 1]);
    __syncthreads();
    const int fl = tid >> 2, ch = tid & 3;
    const short8 v0 = *(const short8*)((const short*)tbuf + fl * 72 + ch * 16);
    const short8 v1 = *(const short8*)((const short*)tbuf + fl * 72 + ch * 16 + 8);
    ushort_t* dst = WhbT + ((size_t)(b * S) + col0 + fl) * NN + j0 + ch * 16;
    *(short8*)dst = v0;
    *(short8*)(dst + 8) = v1;

    if constexpr (PACK) { if (!(id & 1)) do_pack(); }
}

// ---------------------------------------------------------------------------
// Fused attention apply, stats-free (unnormalized P + MFMA-ones row sums).
// s2 arrives pre-scaled by log2e. P packed via v_cvt_pk_bf16_f32.
// OUT_BF16=1 (JQ=1): normalize in epilogue, write hcat bf16.
// OUT_BF16=0 (JQ=4): write bf16 raw partials + f32 per-quarter row sums.
// Wh^T chunks double-buffered in LDS, 1 barrier/chunk, prefetch depth 2.
// ---------------------------------------------------------------------------
template <int H, int JQ, int OUT_BF16>
__global__ __launch_bounds__(256, 4) void apply_kernel(
    const ushort_t* __restrict__ WhbT, const int S,
    const float* __restrict__ s1, const float* __restrict__ s2,
    const unsigned* __restrict__ bm32,
    void* __restrict__ outp, float* __restrict__ sums) {
    constexpr int JLEN = NN / JQ;
    constexpr int BW = JLEN / 32;
    constexpr int NCH = JLEN / 64;
    constexpr int SB = 2 * 8192;
    constexpr int UBUF = SB;                       // obuf [64][72] bf16 = 9216 < SB

    __shared__ __align__(16) float s2s[JLEN];
    __shared__ unsigned bs[64][BW + 1];
    __shared__ __align__(16) char ubuf[UBUF];
    auto stage = (unsigned (*)[64][32])ubuf;       // [2][64 f-rows][8 slots x 4 u32]

    const int Bk = blockIdx.x;
    const int lid = (Bk & 7) * 128 + (Bk >> 3);    // XCD-contiguous logical id
    const int it = lid & 15;
    const int b  = (lid >> 4) & 15;
    const int z  = lid >> 8;
    const int h  = (H > 1) ? z : 0;
    const int jq = (JQ > 1) ? z : 0;
    const int j0g = jq * JLEN;

    const int tid = threadIdx.x;
    const int w = tid >> 6, l = tid & 63;
    const int lo = l & 15, kg = l >> 4;
    const int iloc = w * 16 + lo;
    const int rbase = b * NN + it * 64;
    const int gi = rbase + iloc;
    const int hb = h * (BB * NN);

    const ushort_t* __restrict__ whb = WhbT + ((size_t)(b * S + h * FH)) * NN + j0g;

    const int r0 = tid >> 3, st = tid & 7;
    const int sw = (st ^ (r0 & 7)) * 4;
    const size_t ga = (size_t)r0 * NN + st * 8;
    const size_t gb = (size_t)(r0 + 32) * NN + st * 8;

    // prologue: chunk-0 loads (hidden under s2/bits staging)
    int4 cva0 = *(const int4*)(whb + ga);
    int4 cva1 = *(const int4*)(whb + gb);

    // stage s2 (already log2e-scaled) + adjacency bits
    const float* __restrict__ s2g = s2 + hb + b * NN + j0g;
    for (int k = tid; k < JLEN / 4; k += 256)
        *(float4*)(s2s + k * 4) = *(const float4*)(s2g + k * 4);
    for (int idx = tid; idx < 64 * BW; idx += 256) {
        int r = idx / BW, wd = idx - r * BW;
        bs[r][wd] = bm32[(size_t)(rbase + r) * 32 + (j0g >> 5) + wd];
    }

    const float s1L = s1[hb + gi] * LOG2E;
    const float Arow = s1L;
    const float Brow = s1L * 0.2f;

    short8 ones;
    #pragma unroll
    for (int e = 0; e < 8; ++e) ones[e] = (short)0x3F80;   // bf16 1.0

    f32x4 acc[4];
    #pragma unroll
    for (int fb = 0; fb < 4; ++fb) acc[fb] = (f32x4){0.f, 0.f, 0.f, 0.f};
    f32x4 accs = (f32x4){0.f, 0.f, 0.f, 0.f};

    // write chunk 0 into buf 0; reload cva with chunk 1; single barrier
    *(int4*)&stage[0][r0][sw] = cva0;
    *(int4*)&stage[0][r0 + 32][sw] = cva1;
    if (1 < NCH) {
        cva0 = *(const int4*)(whb + 64 + ga);
        cva1 = *(const int4*)(whb + 64 + gb);
    }
    __syncthreads();

    #pragma unroll
    for (int c = 0; c < NCH; ++c) {
        int4 cvb0, cvb1;
        if (c + 2 < NCH) {                          // issue chunk c+2 loads
            const ushort_t* src = whb + (c + 2) * 64;
            cvb0 = *(const int4*)(src + ga);
            cvb1 = *(const int4*)(src + gb);
        }
        #pragma unroll
        for (int ks = 0; ks < 2; ++ks) {
            const int kb = c * 64 + ks * 32 + kg * 8;
            const unsigned byte = (bs[iloc][c * 2 + ks] >> (kg * 8)) & 0xFF;
            const float4 sa = *(const float4*)(s2s + kb);
            const float4 sb = *(const float4*)(s2s + kb + 4);
            const float s2r[8] = {sa.x, sa.y, sa.z, sa.w, sb.x, sb.y, sb.z, sb.w};
            float pv[8];
            #pragma unroll
            for (int e = 0; e < 8; ++e) {
                const float t = s2r[e];
                const float u = Arow + t;
                const float v = __builtin_fmaf(t, 0.2f, Brow);
                float ev = fmaxf(u, v);
                ev = ((byte >> e) & 1) ? ev : -1.0e5f;
                pv[e] = __builtin_amdgcn_exp2f(ev);
            }
            u32x4 pk;
            pk[0] = pkbf(pv[0], pv[1]); pk[1] = pkbf(pv[2], pv[3]);
            pk[2] = pkbf(pv[4], pv[5]); pk[3] = pkbf(pv[6], pv[7]);
            const short8 bfr = __builtin_bit_cast(short8, pk);
            __builtin_amdgcn_s_setprio(1);
            #pragma unroll
            for (int fb = 0; fb < 4; ++fb) {
                const int row = fb * 16 + lo;
                const int slot = (ks * 4 + kg) ^ (row & 7);
                const short8 afr = *(const short8*)&stage[c & 1][row][slot * 4];
                acc[fb] = __builtin_amdgcn_mfma_f32_16x16x32_bf16(afr, bfr, acc[fb], 0, 0, 0);
            }
            accs = __builtin_amdgcn_mfma_f32_16x16x32_bf16(ones, bfr, accs, 0, 0, 0);
            __builtin_amdgcn_s_setprio(0);
        }
        if (c + 1 < NCH) {                          // write landed chunk c+1
            *(int4*)&stage[(c + 1) & 1][r0][sw] = cva0;
            *(int4*)&stage[(c + 1) & 1][r0 + 32][sw] = cva1;
        }
        cva0 = cvb0;
        cva1 = cvb1;
        __syncthreads();
    }

    // accs[r] = sum_j P[i=iloc][j] over this block's j-range (all r, all kg)
    // lane (lo,kg) holds i = iloc, f = fb*16 + kg*4 + r
    const float inv = OUT_BF16 ? (1.0f / accs[0]) : 1.0f;
    if (!OUT_BF16 && kg == 0)
        sums[(size_t)jq * (BB * NN) + rbase + iloc] = accs[0];

    unsigned* ot = (unsigned*)ubuf;                // [64][36] u32 view of [64][72] bf16
    #pragma unroll
    for (int fb = 0; fb < 4; ++fb)
        #pragma unroll
        for (int rp = 0; rp < 2; ++rp)
            ot[iloc * 36 + fb * 8 + kg * 2 + rp] =
                pkbf(acc[fb][rp * 2] * inv, acc[fb][rp * 2 + 1] * inv);
    __syncthreads();
    const int i2 = tid >> 2, ch = tid & 3;
    const short8 v0 = *(const short8*)((const short*)ubuf + i2 * 72 + ch * 16);
    const short8 v1 = *(const short8*)((const short*)ubuf + i2 * 72 + ch * 16 + 8);
    if constexpr (OUT_BF16) {
        ushort_t* dst = (ushort_t*)outp + (size_t)(b * NN + it * 64 + i2) * 256 + h * FH + ch * 16;
        *(short8*)dst = v0;
        *(short8*)(dst + 8) = v1;
    } else {
        ushort_t* dst = (ushort_t*)outp + (size_t)jq * (BB * NN * FH)
                      + (size_t)(b * NN + it * 64 + i2) * FH + ch * 16;
        *(short8*)dst = v0;
        *(short8*)(dst + 8) = v1;
    }
}

// ---------------------------------------------------------------------------
// Mean: combine 4 bf16 j-partials, normalize by summed row-sums, ELU,
// partial mean, atomicAdd into (pack-zeroed) out. Grid (16 b, 16 chunks).
// ---------------------------------------------------------------------------
__global__ __launch_bounds__(256) void mean1_kernel(const ushort_t* __restrict__ part,
                                                    const float* __restrict__ sums,
                                                    float* __restrict__ out) {
    const int b = blockIdx.x, ck = blockIdx.y;
    const int tid = threadIdx.x;
    const int f = tid & 63, g = tid >> 6;
    float acc = 0.f;
    #pragma unroll
    for (int i = g; i < 64; i += 4) {
        const int row = b * NN + ck * 64 + i;
        const float srow = sums[row] + sums[row + 16384]
                         + sums[row + 32768] + sums[row + 49152];
        float v = 0.f;
        #pragma unroll
        for (int q = 0; q < 4; ++q)
            v += bf2f((short)part[(size_t)q * 1048576 + (size_t)row * FH + f]);
        v /= srow;
        v = (v > 0.f) ? v : (__builtin_amdgcn_exp2f(v * LOG2E) - 1.0f);
        acc += v;
    }
    __shared__ float r[4][64];
    r[g][f] = acc;
    __syncthreads();
    if (g == 0)
        atomicAdd(&out[b * FH + f],
                  (r[0][f] + r[1][f] + r[2][f] + r[3][f]) * (1.0f / NN));
}

extern "C" void kernel_launch(void* const* d_in, const int* in_sizes, int n_in,
                              void* d_out, int out_size, void* d_ws, size_t ws_size,
                              hipStream_t stream) {
    const float* x       = (const float*)d_in[0];
    const int*   adj     = (const int*)d_in[1];
    const float* W_heads = (const float*)d_in[2];
    const float* a_heads = (const float*)d_in[3];
    const float* W_out   = (const float*)d_in[4];
    const float* a_out   = (const float*)d_in[5];
    float* out = (float*)d_out;
    float* f0  = (float*)d_ws;

    // workspace (float offsets). part (bf16, 8MB) overlays hcat (dead after gemm2).
    ushort_t* hcat  = (ushort_t*)f0;                     // [16384][256] bf16, 8 MB
    ushort_t* part  = (ushort_t*)f0;                     // [4][16384][64] bf16, 8 MB
    ushort_t* WhbT1 = (ushort_t*)(f0 + 2097152);         // [16][256][1024] bf16, 8 MB
    ushort_t* WhbT2 = (ushort_t*)(f0 + 4194304);         // [16][64][1024] bf16, 2 MB
    u64*      bmask = (u64*)(f0 + 4718592);              // [16384][16] u64, 2 MB
    ushort_t* WbT1  = (ushort_t*)(f0 + 5242880);         // [256][256] bf16
    ushort_t* WbT2  = (ushort_t*)(f0 + 5275648);         // [64][256] bf16
    float*    s1_1  = f0 + 5283840;                      // [4][16384]
    float*    s2_1  = s1_1 + 65536;
    float*    s1_2  = s2_1 + 65536;                      // [16384]
    float*    s2_2  = s1_2 + 16384;
    float*    sums2 = s2_2 + 16384;                      // [4][16384]

    dim3 blk(256);

    // weight transpose + out zeroing (adj packing fused into gemm1)
    packw_kernel<<<dim3(320), blk, 0, stream>>>(W_heads, W_out, WbT1, WbT2, out);

    // layer 1 (gemm1 also packs the adjacency bitmask, staggered even/odd)
    gemm_fused<0, 1><<<dim3(4, 256), blk, 0, stream>>>(x, WbT1, a_heads, WhbT1, s1_1, s2_1, 256,
                                                       adj, bmask);
    apply_kernel<NH, 1, 1><<<dim3(1024), blk, 0, stream>>>(WhbT1, 256, s1_1, s2_1,
                                                           (const unsigned*)bmask, hcat, nullptr);

    // layer 2
    gemm_fused<1, 0><<<dim3(1, 256), blk, 0, stream>>>(hcat, WbT2, a_out, WhbT2, s1_2, s2_2, 64,
                                                       nullptr, nullptr);
    apply_kernel<1, 4, 0><<<dim3(1024), blk, 0, stream>>>(WhbT2, 64, s1_2, s2_2,
                                                          (const unsigned*)bmask, part, sums2);

    // combine partials + normalize + elu + mean (atomic tail; out zeroed in packw)
    mean1_kernel<<<dim3(BB, 16), blk, 0, stream>>>(part, sums2, out);
}

// Round 20
// 90.994 us; speedup vs baseline: 1.1757x; 1.0315x over previous
//
#include <hip/hip_runtime.h>
#include <math.h>

#define BB 16
#define NN 1024
#define FH 64
#define NH 4
#define LOG2E 1.4426950408889634f

typedef __attribute__((ext_vector_type(8))) short short8;
typedef __attribute__((ext_vector_type(4))) float f32x4;
typedef __attribute__((ext_vector_type(4))) unsigned u32x4;
typedef unsigned long long u64;
typedef unsigned short ushort_t;

__device__ inline unsigned f2bf(float x) {
    unsigned u = __builtin_bit_cast(unsigned, x);
    u += 0x7fff + ((u >> 16) & 1);   // round-to-nearest-even
    return u >> 16;
}
__device__ inline unsigned pkbf(float lo, float hi) {
    unsigned r;
    asm("v_cvt_pk_bf16_f32 %0, %1, %2" : "=v"(r) : "v"(lo), "v"(hi));
    return r;
}
__device__ inline float bf2f(short v) {
    return __builtin_bit_cast(float, (unsigned)((unsigned short)v) << 16);
}

// ---------------------------------------------------------------------------
// Weight transpose to bf16 (320 blocks) + zero d_out (block 0).
// adj packing lives in gemm1 (overlaps HBM with MFMA).
// ---------------------------------------------------------------------------
__global__ void packw_kernel(const float* __restrict__ Whd, const float* __restrict__ Wo,
                             ushort_t* __restrict__ BT1, ushort_t* __restrict__ BT2,
                             float* __restrict__ outz) {
    const int col = blockIdx.x, k = threadIdx.x;
    if (col < 256)      BT1[col * 256 + k] = (ushort_t)f2bf(Whd[(col >> 6) * 16384 + k * 64 + (col & 63)]);
    else if (col < 320) BT2[(col - 256) * 256 + k] = (ushort_t)f2bf(Wo[k * 64 + (col - 256)]);
    if (col == 0) {
        #pragma unroll
        for (int i = 0; i < 4; ++i) outz[i * 256 + k] = 0.f;
    }
}

// ---------------------------------------------------------------------------
// Fused MFMA GEMM + score epilogue + bf16 transposed WhbT output.
// PACK=1 (layer 1): each block packs 16 adj rows into the bitmask via
// int4-PAIR loads (32B/lane) + per-lane byte packing + byte stores — the
// byte array layout is bit-identical to the u32 mask words apply reads.
// Even/odd stagger: odd blocks pack before the GEMM, even blocks after.
// s2 is stored PRE-SCALED by log2e (consumed only by apply).
// ---------------------------------------------------------------------------
template <int A_BF16, int PACK>
__global__ __launch_bounds__(256, 4) void gemm_fused(
    const void* __restrict__ Ap, const ushort_t* __restrict__ BT,
    const float* __restrict__ av, ushort_t* __restrict__ WhbT,
    float* __restrict__ s1, float* __restrict__ s2, const int S,
    const int* __restrict__ adj, u64* __restrict__ bm) {
    constexpr int K = 256;
    __shared__ __align__(16) short tbuf[64][72];
    const int tid = threadIdx.x;
    const int w = tid >> 6, l = tid & 63, lo = l & 15, kg = l >> 4;

    const int nx = gridDim.x;
    const int id = blockIdx.y * nx + blockIdx.x;
    const int nwg = nx * gridDim.y;
    const int lid = (id & 7) * (nwg >> 3) + (id >> 3);   // bijective: nwg % 8 == 0
    const int row0 = (lid / nx) * 64, col0 = (lid % nx) * 64;

    const int b = row0 >> 10, j0 = row0 & (NN - 1);
    const int hsel = col0 >> 6;

    // adjacency packing: 16 rows/block (4 per wave); lane l packs byte for
    // elements 8l..8l+7 from two int4 loads; byte m of a row covers j=8m..8m+7
    // (u32-word view identical to the ballot-era bm32 layout).
    auto do_pack = [&]() {
        const int rowb = id * 16 + w * 4;
        unsigned char* __restrict__ bm8 = (unsigned char*)bm;
        #pragma unroll
        for (int rr = 0; rr < 4; ++rr) {
            const int* __restrict__ ar = adj + (size_t)(rowb + rr) * NN;
            #pragma unroll
            for (int half = 0; half < 2; ++half) {
                const int4 v0 = *(const int4*)(ar + half * 512 + 8 * l);
                const int4 v1 = *(const int4*)(ar + half * 512 + 8 * l + 4);
                unsigned byte = (unsigned)(v0.x > 0)
                              | ((unsigned)(v0.y > 0) << 1)
                              | ((unsigned)(v0.z > 0) << 2)
                              | ((unsigned)(v0.w > 0) << 3)
                              | ((unsigned)(v1.x > 0) << 4)
                              | ((unsigned)(v1.y > 0) << 5)
                              | ((unsigned)(v1.z > 0) << 6)
                              | ((unsigned)(v1.w > 0) << 7);
                bm8[(size_t)(rowb + rr) * 128 + half * 64 + l] = (unsigned char)byte;
            }
        }
    };
    if constexpr (PACK) { if (id & 1) do_pack(); }

    f32x4 acc[4];
    #pragma unroll
    for (int cb = 0; cb < 4; ++cb) acc[cb] = (f32x4){0.f, 0.f, 0.f, 0.f};

    if (A_BF16) {
        const ushort_t* __restrict__ arow = (const ushort_t*)Ap + (size_t)(row0 + w * 16 + lo) * K;
        #pragma unroll
        for (int ks = 0; ks < 8; ++ks) {
            const int k0 = ks * 32 + kg * 8;
            const short8 af = *(const short8*)(arow + k0);
            #pragma unroll
            for (int cb = 0; cb < 4; ++cb) {
                const short8 bf = *(const short8*)(BT + (size_t)(col0 + cb * 16 + lo) * K + k0);
                acc[cb] = __builtin_amdgcn_mfma_f32_16x16x32_bf16(af, bf, acc[cb], 0, 0, 0);
            }
        }
    } else {
        const float* __restrict__ arow = (const float*)Ap + (size_t)(row0 + w * 16 + lo) * K;
        #pragma unroll
        for (int ks = 0; ks < 8; ++ks) {
            const int k0 = ks * 32 + kg * 8;
            const float4 a0 = *(const float4*)(arow + k0);
            const float4 a1 = *(const float4*)(arow + k0 + 4);
            u32x4 ap;
            ap[0] = pkbf(a0.x, a0.y); ap[1] = pkbf(a0.z, a0.w);
            ap[2] = pkbf(a1.x, a1.y); ap[3] = pkbf(a1.z, a1.w);
            const short8 af = __builtin_bit_cast(short8, ap);
            #pragma unroll
            for (int cb = 0; cb < 4; ++cb) {
                const short8 bf = *(const short8*)(BT + (size_t)(col0 + cb * 16 + lo) * K + k0);
                acc[cb] = __builtin_amdgcn_mfma_f32_16x16x32_bf16(af, bf, acc[cb], 0, 0, 0);
            }
        }
    }

    float a1v[4], a2v[4];
    #pragma unroll
    for (int cb = 0; cb < 4; ++cb) {
        a1v[cb] = av[hsel * 128 + cb * 16 + lo];
        a2v[cb] = av[hsel * 128 + 64 + cb * 16 + lo];
    }
    float sp1[4], sp2[4];
    #pragma unroll
    for (int r = 0; r < 4; ++r) {
        sp1[r] = acc[0][r] * a1v[0] + acc[1][r] * a1v[1] + acc[2][r] * a1v[2] + acc[3][r] * a1v[3];
        sp2[r] = acc[0][r] * a2v[0] + acc[1][r] * a2v[1] + acc[2][r] * a2v[2] + acc[3][r] * a2v[3];
    }
    #pragma unroll
    for (int m = 1; m < 16; m <<= 1) {
        #pragma unroll
        for (int r = 0; r < 4; ++r) {
            sp1[r] += __shfl_xor(sp1[r], m);
            sp2[r] += __shfl_xor(sp2[r], m);
        }
    }
    if (lo == 0) {
        #pragma unroll
        for (int r = 0; r < 4; ++r) {
            const int R = row0 + w * 16 + kg * 4 + r;
            s1[hsel * (BB * NN) + R] = sp1[r];
            s2[hsel * (BB * NN) + R] = sp2[r] * LOG2E;
        }
    }

    #pragma unroll
    for (int cb = 0; cb < 4; ++cb)
        #pragma unroll
        for (int rp = 0; rp < 2; ++rp)
            ((unsigned*)tbuf)[(cb * 16 + lo) * 36 + w * 8 + kg * 2 + rp] =
                pkbf(acc[cb][rp * 2], acc[cb][rp * 2 + 1]);
    __syncthreads();
    const int fl = tid >> 2, ch = tid & 3;
    const short8 v0 = *(const short8*)((const short*)tbuf + fl * 72 + ch * 16);
    const short8 v1 = *(const short8*)((const short*)tbuf + fl * 72 + ch * 16 + 8);
    ushort_t* dst = WhbT + ((size_t)(b * S) + col0 + fl) * NN + j0 + ch * 16;
    *(short8*)dst = v0;
    *(short8*)(dst + 8) = v1;

    if constexpr (PACK) { if (!(id & 1)) do_pack(); }
}

// ---------------------------------------------------------------------------
// Fused attention apply, stats-free (unnormalized P + MFMA-ones row sums).
// s2 arrives pre-scaled by log2e. P packed via v_cvt_pk_bf16_f32.
// OUT_BF16=1 (JQ=1): normalize in epilogue, write hcat bf16.
// OUT_BF16=0 (JQ=4): write bf16 raw partials + f32 per-quarter row sums.
// Wh^T chunks double-buffered in LDS, 1 barrier/chunk, prefetch depth 2.
// ---------------------------------------------------------------------------
template <int H, int JQ, int OUT_BF16>
__global__ __launch_bounds__(256, 4) void apply_kernel(
    const ushort_t* __restrict__ WhbT, const int S,
    const float* __restrict__ s1, const float* __restrict__ s2,
    const unsigned* __restrict__ bm32,
    void* __restrict__ outp, float* __restrict__ sums) {
    constexpr int JLEN = NN / JQ;
    constexpr int BW = JLEN / 32;
    constexpr int NCH = JLEN / 64;
    constexpr int SB = 2 * 8192;
    constexpr int UBUF = SB;                       // obuf [64][72] bf16 = 9216 < SB

    __shared__ __align__(16) float s2s[JLEN];
    __shared__ unsigned bs[64][BW + 1];
    __shared__ __align__(16) char ubuf[UBUF];
    auto stage = (unsigned (*)[64][32])ubuf;       // [2][64 f-rows][8 slots x 4 u32]

    const int Bk = blockIdx.x;
    const int lid = (Bk & 7) * 128 + (Bk >> 3);    // XCD-contiguous logical id
    const int it = lid & 15;
    const int b  = (lid >> 4) & 15;
    const int z  = lid >> 8;
    const int h  = (H > 1) ? z : 0;
    const int jq = (JQ > 1) ? z : 0;
    const int j0g = jq * JLEN;

    const int tid = threadIdx.x;
    const int w = tid >> 6, l = tid & 63;
    const int lo = l & 15, kg = l >> 4;
    const int iloc = w * 16 + lo;
    const int rbase = b * NN + it * 64;
    const int gi = rbase + iloc;
    const int hb = h * (BB * NN);

    const ushort_t* __restrict__ whb = WhbT + ((size_t)(b * S + h * FH)) * NN + j0g;

    const int r0 = tid >> 3, st = tid & 7;
    const int sw = (st ^ (r0 & 7)) * 4;
    const size_t ga = (size_t)r0 * NN + st * 8;
    const size_t gb = (size_t)(r0 + 32) * NN + st * 8;

    // prologue: chunk-0 loads (hidden under s2/bits staging)
    int4 cva0 = *(const int4*)(whb + ga);
    int4 cva1 = *(const int4*)(whb + gb);

    // stage s2 (already log2e-scaled) + adjacency bits
    const float* __restrict__ s2g = s2 + hb + b * NN + j0g;
    for (int k = tid; k < JLEN / 4; k += 256)
        *(float4*)(s2s + k * 4) = *(const float4*)(s2g + k * 4);
    for (int idx = tid; idx < 64 * BW; idx += 256) {
        int r = idx / BW, wd = idx - r * BW;
        bs[r][wd] = bm32[(size_t)(rbase + r) * 32 + (j0g >> 5) + wd];
    }

    const float s1L = s1[hb + gi] * LOG2E;
    const float Arow = s1L;
    const float Brow = s1L * 0.2f;

    short8 ones;
    #pragma unroll
    for (int e = 0; e < 8; ++e) ones[e] = (short)0x3F80;   // bf16 1.0

    f32x4 acc[4];
    #pragma unroll
    for (int fb = 0; fb < 4; ++fb) acc[fb] = (f32x4){0.f, 0.f, 0.f, 0.f};
    f32x4 accs = (f32x4){0.f, 0.f, 0.f, 0.f};

    // write chunk 0 into buf 0; reload cva with chunk 1; single barrier
    *(int4*)&stage[0][r0][sw] = cva0;
    *(int4*)&stage[0][r0 + 32][sw] = cva1;
    if (1 < NCH) {
        cva0 = *(const int4*)(whb + 64 + ga);
        cva1 = *(const int4*)(whb + 64 + gb);
    }
    __syncthreads();

    #pragma unroll
    for (int c = 0; c < NCH; ++c) {
        int4 cvb0, cvb1;
        if (c + 2 < NCH) {                          // issue chunk c+2 loads
            const ushort_t* src = whb + (c + 2) * 64;
            cvb0 = *(const int4*)(src + ga);
            cvb1 = *(const int4*)(src + gb);
        }
        #pragma unroll
        for (int ks = 0; ks < 2; ++ks) {
            const int kb = c * 64 + ks * 32 + kg * 8;
            const unsigned byte = (bs[iloc][c * 2 + ks] >> (kg * 8)) & 0xFF;
            const float4 sa = *(const float4*)(s2s + kb);
            const float4 sb = *(const float4*)(s2s + kb + 4);
            const float s2r[8] = {sa.x, sa.y, sa.z, sa.w, sb.x, sb.y, sb.z, sb.w};
            float pv[8];
            #pragma unroll
            for (int e = 0; e < 8; ++e) {
                const float t = s2r[e];
                const float u = Arow + t;
                const float v = __builtin_fmaf(t, 0.2f, Brow);
                float ev = fmaxf(u, v);
                ev = ((byte >> e) & 1) ? ev : -1.0e5f;
                pv[e] = __builtin_amdgcn_exp2f(ev);
            }
            u32x4 pk;
            pk[0] = pkbf(pv[0], pv[1]); pk[1] = pkbf(pv[2], pv[3]);
            pk[2] = pkbf(pv[4], pv[5]); pk[3] = pkbf(pv[6], pv[7]);
            const short8 bfr = __builtin_bit_cast(short8, pk);
            __builtin_amdgcn_s_setprio(1);
            #pragma unroll
            for (int fb = 0; fb < 4; ++fb) {
                const int row = fb * 16 + lo;
                const int slot = (ks * 4 + kg) ^ (row & 7);
                const short8 afr = *(const short8*)&stage[c & 1][row][slot * 4];
                acc[fb] = __builtin_amdgcn_mfma_f32_16x16x32_bf16(afr, bfr, acc[fb], 0, 0, 0);
            }
            accs = __builtin_amdgcn_mfma_f32_16x16x32_bf16(ones, bfr, accs, 0, 0, 0);
            __builtin_amdgcn_s_setprio(0);
        }
        if (c + 1 < NCH) {                          // write landed chunk c+1
            *(int4*)&stage[(c + 1) & 1][r0][sw] = cva0;
            *(int4*)&stage[(c + 1) & 1][r0 + 32][sw] = cva1;
        }
        cva0 = cvb0;
        cva1 = cvb1;
        __syncthreads();
    }

    // accs[r] = sum_j P[i=iloc][j] over this block's j-range (all r, all kg)
    // lane (lo,kg) holds i = iloc, f = fb*16 + kg*4 + r
    const float inv = OUT_BF16 ? (1.0f / accs[0]) : 1.0f;
    if (!OUT_BF16 && kg == 0)
        sums[(size_t)jq * (BB * NN) + rbase + iloc] = accs[0];

    unsigned* ot = (unsigned*)ubuf;                // [64][36] u32 view of [64][72] bf16
    #pragma unroll
    for (int fb = 0; fb < 4; ++fb)
        #pragma unroll
        for (int rp = 0; rp < 2; ++rp)
            ot[iloc * 36 + fb * 8 + kg * 2 + rp] =
                pkbf(acc[fb][rp * 2] * inv, acc[fb][rp * 2 + 1] * inv);
    __syncthreads();
    const int i2 = tid >> 2, ch = tid & 3;
    const short8 v0 = *(const short8*)((const short*)ubuf + i2 * 72 + ch * 16);
    const short8 v1 = *(const short8*)((const short*)ubuf + i2 * 72 + ch * 16 + 8);
    if constexpr (OUT_BF16) {
        ushort_t* dst = (ushort_t*)outp + (size_t)(b * NN + it * 64 + i2) * 256 + h * FH + ch * 16;
        *(short8*)dst = v0;
        *(short8*)(dst + 8) = v1;
    } else {
        ushort_t* dst = (ushort_t*)outp + (size_t)jq * (BB * NN * FH)
                      + (size_t)(b * NN + it * 64 + i2) * FH + ch * 16;
        *(short8*)dst = v0;
        *(short8*)(dst + 8) = v1;
    }
}

// ---------------------------------------------------------------------------
// Mean: combine 4 bf16 j-partials, normalize by summed row-sums, ELU,
// partial mean, atomicAdd into (packw-zeroed) out. Grid (16 b, 16 chunks).
// ---------------------------------------------------------------------------
__global__ __launch_bounds__(256) void mean1_kernel(const ushort_t* __restrict__ part,
                                                    const float* __restrict__ sums,
                                                    float* __restrict__ out) {
    const int b = blockIdx.x, ck = blockIdx.y;
    const int tid = threadIdx.x;
    const int f = tid & 63, g = tid >> 6;
    float acc = 0.f;
    #pragma unroll
    for (int i = g; i < 64; i += 4) {
        const int row = b * NN + ck * 64 + i;
        const float srow = sums[row] + sums[row + 16384]
                         + sums[row + 32768] + sums[row + 49152];
        float v = 0.f;
        #pragma unroll
        for (int q = 0; q < 4; ++q)
            v += bf2f((short)part[(size_t)q * 1048576 + (size_t)row * FH + f]);
        v /= srow;
        v = (v > 0.f) ? v : (__builtin_amdgcn_exp2f(v * LOG2E) - 1.0f);
        acc += v;
    }
    __shared__ float r[4][64];
    r[g][f] = acc;
    __syncthreads();
    if (g == 0)
        atomicAdd(&out[b * FH + f],
                  (r[0][f] + r[1][f] + r[2][f] + r[3][f]) * (1.0f / NN));
}

extern "C" void kernel_launch(void* const* d_in, const int* in_sizes, int n_in,
                              void* d_out, int out_size, void* d_ws, size_t ws_size,
                              hipStream_t stream) {
    const float* x       = (const float*)d_in[0];
    const int*   adj     = (const int*)d_in[1];
    const float* W_heads = (const float*)d_in[2];
    const float* a_heads = (const float*)d_in[3];
    const float* W_out   = (const float*)d_in[4];
    const float* a_out   = (const float*)d_in[5];
    float* out = (float*)d_out;
    float* f0  = (float*)d_ws;

    // workspace (float offsets). part (bf16, 8MB) overlays hcat (dead after gemm2).
    ushort_t* hcat  = (ushort_t*)f0;                     // [16384][256] bf16, 8 MB
    ushort_t* part  = (ushort_t*)f0;                     // [4][16384][64] bf16, 8 MB
    ushort_t* WhbT1 = (ushort_t*)(f0 + 2097152);         // [16][256][1024] bf16, 8 MB
    ushort_t* WhbT2 = (ushort_t*)(f0 + 4194304);         // [16][64][1024] bf16, 2 MB
    u64*      bmask = (u64*)(f0 + 4718592);              // [16384][16] u64, 2 MB
    ushort_t* WbT1  = (ushort_t*)(f0 + 5242880);         // [256][256] bf16
    ushort_t* WbT2  = (ushort_t*)(f0 + 5275648);         // [64][256] bf16
    float*    s1_1  = f0 + 5283840;                      // [4][16384]
    float*    s2_1  = s1_1 + 65536;
    float*    s1_2  = s2_1 + 65536;                      // [16384]
    float*    s2_2  = s1_2 + 16384;
    float*    sums2 = s2_2 + 16384;                      // [4][16384]

    dim3 blk(256);

    // weight transpose + out zeroing (adj packing fused into gemm1)
    packw_kernel<<<dim3(320), blk, 0, stream>>>(W_heads, W_out, WbT1, WbT2, out);

    // layer 1 (gemm1 also packs the adjacency bitmask, staggered even/odd)
    gemm_fused<0, 1><<<dim3(4, 256), blk, 0, stream>>>(x, WbT1, a_heads, WhbT1, s1_1, s2_1, 256,
                                                       adj, bmask);
    apply_kernel<NH, 1, 1><<<dim3(1024), blk, 0, stream>>>(WhbT1, 256, s1_1, s2_1,
                                                           (const unsigned*)bmask, hcat, nullptr);

    // layer 2
    gemm_fused<1, 0><<<dim3(1, 256), blk, 0, stream>>>(hcat, WbT2, a_out, WhbT2, s1_2, s2_2, 64,
                                                       nullptr, nullptr);
    apply_kernel<1, 4, 0><<<dim3(1024), blk, 0, stream>>>(WhbT2, 64, s1_2, s2_2,
                                                          (const unsigned*)bmask, part, sums2);

    // combine partials + normalize + elu + mean (atomic tail; out zeroed in packw)
    mean1_kernel<<<dim3(BB, 16), blk, 0, stream>>>(part, sums2, out);
}

// Round 21
// 90.853 us; speedup vs baseline: 1.1776x; 1.0016x over previous
//
#include <hip/hip_runtime.h>
#include <math.h>

#define BB 16
#define NN 1024
#define FH 64
#define NH 4
#define LOG2E 1.4426950408889634f

typedef __attribute__((ext_vector_type(8))) short short8;
typedef __attribute__((ext_vector_type(4))) float f32x4;
typedef __attribute__((ext_vector_type(4))) unsigned u32x4;
typedef unsigned long long u64;
typedef unsigned short ushort_t;

__device__ inline unsigned f2bf(float x) {
    unsigned u = __builtin_bit_cast(unsigned, x);
    u += 0x7fff + ((u >> 16) & 1);   // round-to-nearest-even
    return u >> 16;
}
__device__ inline unsigned pkbf(float lo, float hi) {
    unsigned r;
    asm("v_cvt_pk_bf16_f32 %0, %1, %2" : "=v"(r) : "v"(lo), "v"(hi));
    return r;
}
__device__ inline float bf2f(short v) {
    return __builtin_bit_cast(float, (unsigned)((unsigned short)v) << 16);
}

// ---------------------------------------------------------------------------
// Weight transpose to bf16 (320 blocks) + zero d_out (block 0).
// adj packing lives in gemm1 (overlaps HBM with MFMA).
// ---------------------------------------------------------------------------
__global__ void packw_kernel(const float* __restrict__ Whd, const float* __restrict__ Wo,
                             ushort_t* __restrict__ BT1, ushort_t* __restrict__ BT2,
                             float* __restrict__ outz) {
    const int col = blockIdx.x, k = threadIdx.x;
    if (col < 256)      BT1[col * 256 + k] = (ushort_t)f2bf(Whd[(col >> 6) * 16384 + k * 64 + (col & 63)]);
    else if (col < 320) BT2[(col - 256) * 256 + k] = (ushort_t)f2bf(Wo[k * 64 + (col - 256)]);
    if (col == 0) {
        #pragma unroll
        for (int i = 0; i < 4; ++i) outz[i * 256 + k] = 0.f;
    }
}

// ---------------------------------------------------------------------------
// Fused MFMA GEMM + score epilogue + bf16 transposed WhbT output.
// PACK=1 (layer 1): each block packs 16 adj rows into the bitmask via
// int4-PAIR loads (32B/lane) + per-lane byte packing + byte stores.
// Even/odd stagger: odd blocks pack before the GEMM, even blocks after.
// s2 is stored PRE-SCALED by log2e (consumed only by apply).
// ---------------------------------------------------------------------------
template <int A_BF16, int PACK>
__global__ __launch_bounds__(256, 4) void gemm_fused(
    const void* __restrict__ Ap, const ushort_t* __restrict__ BT,
    const float* __restrict__ av, ushort_t* __restrict__ WhbT,
    float* __restrict__ s1, float* __restrict__ s2, const int S,
    const int* __restrict__ adj, u64* __restrict__ bm) {
    constexpr int K = 256;
    __shared__ __align__(16) short tbuf[64][72];
    const int tid = threadIdx.x;
    const int w = tid >> 6, l = tid & 63, lo = l & 15, kg = l >> 4;

    const int nx = gridDim.x;
    const int id = blockIdx.y * nx + blockIdx.x;
    const int nwg = nx * gridDim.y;
    const int lid = (id & 7) * (nwg >> 3) + (id >> 3);   // bijective: nwg % 8 == 0
    const int row0 = (lid / nx) * 64, col0 = (lid % nx) * 64;

    const int b = row0 >> 10, j0 = row0 & (NN - 1);
    const int hsel = col0 >> 6;

    auto do_pack = [&]() {
        const int rowb = id * 16 + w * 4;
        unsigned char* __restrict__ bm8 = (unsigned char*)bm;
        #pragma unroll
        for (int rr = 0; rr < 4; ++rr) {
            const int* __restrict__ ar = adj + (size_t)(rowb + rr) * NN;
            #pragma unroll
            for (int half = 0; half < 2; ++half) {
                const int4 v0 = *(const int4*)(ar + half * 512 + 8 * l);
                const int4 v1 = *(const int4*)(ar + half * 512 + 8 * l + 4);
                unsigned byte = (unsigned)(v0.x > 0)
                              | ((unsigned)(v0.y > 0) << 1)
                              | ((unsigned)(v0.z > 0) << 2)
                              | ((unsigned)(v0.w > 0) << 3)
                              | ((unsigned)(v1.x > 0) << 4)
                              | ((unsigned)(v1.y > 0) << 5)
                              | ((unsigned)(v1.z > 0) << 6)
                              | ((unsigned)(v1.w > 0) << 7);
                bm8[(size_t)(rowb + rr) * 128 + half * 64 + l] = (unsigned char)byte;
            }
        }
    };
    if constexpr (PACK) { if (id & 1) do_pack(); }

    f32x4 acc[4];
    #pragma unroll
    for (int cb = 0; cb < 4; ++cb) acc[cb] = (f32x4){0.f, 0.f, 0.f, 0.f};

    if (A_BF16) {
        const ushort_t* __restrict__ arow = (const ushort_t*)Ap + (size_t)(row0 + w * 16 + lo) * K;
        #pragma unroll
        for (int ks = 0; ks < 8; ++ks) {
            const int k0 = ks * 32 + kg * 8;
            const short8 af = *(const short8*)(arow + k0);
            #pragma unroll
            for (int cb = 0; cb < 4; ++cb) {
                const short8 bf = *(const short8*)(BT + (size_t)(col0 + cb * 16 + lo) * K + k0);
                acc[cb] = __builtin_amdgcn_mfma_f32_16x16x32_bf16(af, bf, acc[cb], 0, 0, 0);
            }
        }
    } else {
        const float* __restrict__ arow = (const float*)Ap + (size_t)(row0 + w * 16 + lo) * K;
        #pragma unroll
        for (int ks = 0; ks < 8; ++ks) {
            const int k0 = ks * 32 + kg * 8;
            const float4 a0 = *(const float4*)(arow + k0);
            const float4 a1 = *(const float4*)(arow + k0 + 4);
            u32x4 ap;
            ap[0] = pkbf(a0.x, a0.y); ap[1] = pkbf(a0.z, a0.w);
            ap[2] = pkbf(a1.x, a1.y); ap[3] = pkbf(a1.z, a1.w);
            const short8 af = __builtin_bit_cast(short8, ap);
            #pragma unroll
            for (int cb = 0; cb < 4; ++cb) {
                const short8 bf = *(const short8*)(BT + (size_t)(col0 + cb * 16 + lo) * K + k0);
                acc[cb] = __builtin_amdgcn_mfma_f32_16x16x32_bf16(af, bf, acc[cb], 0, 0, 0);
            }
        }
    }

    float a1v[4], a2v[4];
    #pragma unroll
    for (int cb = 0; cb < 4; ++cb) {
        a1v[cb] = av[hsel * 128 + cb * 16 + lo];
        a2v[cb] = av[hsel * 128 + 64 + cb * 16 + lo];
    }
    float sp1[4], sp2[4];
    #pragma unroll
    for (int r = 0; r < 4; ++r) {
        sp1[r] = acc[0][r] * a1v[0] + acc[1][r] * a1v[1] + acc[2][r] * a1v[2] + acc[3][r] * a1v[3];
        sp2[r] = acc[0][r] * a2v[0] + acc[1][r] * a2v[1] + acc[2][r] * a2v[2] + acc[3][r] * a2v[3];
    }
    #pragma unroll
    for (int m = 1; m < 16; m <<= 1) {
        #pragma unroll
        for (int r = 0; r < 4; ++r) {
            sp1[r] += __shfl_xor(sp1[r], m);
            sp2[r] += __shfl_xor(sp2[r], m);
        }
    }
    if (lo == 0) {
        #pragma unroll
        for (int r = 0; r < 4; ++r) {
            const int R = row0 + w * 16 + kg * 4 + r;
            s1[hsel * (BB * NN) + R] = sp1[r];
            s2[hsel * (BB * NN) + R] = sp2[r] * LOG2E;
        }
    }

    #pragma unroll
    for (int cb = 0; cb < 4; ++cb)
        #pragma unroll
        for (int rp = 0; rp < 2; ++rp)
            ((unsigned*)tbuf)[(cb * 16 + lo) * 36 + w * 8 + kg * 2 + rp] =
                pkbf(acc[cb][rp * 2], acc[cb][rp * 2 + 1]);
    __syncthreads();
    const int fl = tid >> 2, ch = tid & 3;
    const short8 v0 = *(const short8*)((const short*)tbuf + fl * 72 + ch * 16);
    const short8 v1 = *(const short8*)((const short*)tbuf + fl * 72 + ch * 16 + 8);
    ushort_t* dst = WhbT + ((size_t)(b * S) + col0 + fl) * NN + j0 + ch * 16;
    *(short8*)dst = v0;
    *(short8*)(dst + 8) = v1;

    if constexpr (PACK) { if (!(id & 1)) do_pack(); }
}

// ---------------------------------------------------------------------------
// Fused attention apply, stats-free (unnormalized P + MFMA-ones row sums).
// s2 arrives pre-scaled by log2e. P packed via v_cvt_pk_bf16_f32.
// Wh^T chunks double-buffered in LDS, 1 barrier/chunk, PREFETCH DEPTH 3
// (cva/cvb/cvc rotation; window ~2-3 compute phases covers L2 latency).
// bs staged via int4 loads (16B/lane); LDS row stride BW+4 words keeps
// 16B alignment and 2-way (free) bank access.
// OUT_BF16=1 (JQ=1): normalize in epilogue, write hcat bf16.
// OUT_BF16=0 (JQ=4): write bf16 raw partials + f32 per-quarter row sums.
// ---------------------------------------------------------------------------
template <int H, int JQ, int OUT_BF16>
__global__ __launch_bounds__(256, 4) void apply_kernel(
    const ushort_t* __restrict__ WhbT, const int S,
    const float* __restrict__ s1, const float* __restrict__ s2,
    const unsigned* __restrict__ bm32,
    void* __restrict__ outp, float* __restrict__ sums) {
    constexpr int JLEN = NN / JQ;
    constexpr int BW = JLEN / 32;
    constexpr int BSW = BW + 4;                    // 16B-aligned row stride
    constexpr int NCH = JLEN / 64;
    constexpr int SB = 2 * 8192;
    constexpr int UBUF = SB;                       // obuf [64][72] bf16 = 9216 < SB

    __shared__ __align__(16) float s2s[JLEN];
    __shared__ __align__(16) unsigned bs[64][BSW];
    __shared__ __align__(16) char ubuf[UBUF];
    auto stage = (unsigned (*)[64][32])ubuf;       // [2][64 f-rows][8 slots x 4 u32]

    const int Bk = blockIdx.x;
    const int lid = (Bk & 7) * 128 + (Bk >> 3);    // XCD-contiguous logical id
    const int it = lid & 15;
    const int b  = (lid >> 4) & 15;
    const int z  = lid >> 8;
    const int h  = (H > 1) ? z : 0;
    const int jq = (JQ > 1) ? z : 0;
    const int j0g = jq * JLEN;

    const int tid = threadIdx.x;
    const int w = tid >> 6, l = tid & 63;
    const int lo = l & 15, kg = l >> 4;
    const int iloc = w * 16 + lo;
    const int rbase = b * NN + it * 64;
    const int gi = rbase + iloc;
    const int hb = h * (BB * NN);

    const ushort_t* __restrict__ whb = WhbT + ((size_t)(b * S + h * FH)) * NN + j0g;

    const int r0 = tid >> 3, st = tid & 7;
    const int sw = (st ^ (r0 & 7)) * 4;
    const size_t ga = (size_t)r0 * NN + st * 8;
    const size_t gb = (size_t)(r0 + 32) * NN + st * 8;

    // prologue: chunk-0 loads (hidden under s2/bits staging)
    int4 cva0 = *(const int4*)(whb + ga);
    int4 cva1 = *(const int4*)(whb + gb);

    // stage s2 (already log2e-scaled) + adjacency bits (int4-vectorized)
    const float* __restrict__ s2g = s2 + hb + b * NN + j0g;
    for (int k = tid; k < JLEN / 4; k += 256)
        *(float4*)(s2s + k * 4) = *(const float4*)(s2g + k * 4);
    constexpr int BCH = 64 * BW / 4;               // int4 chunks (512 or 128)
    for (int n = tid; n < BCH; n += 256) {
        const int r = n / (BW / 4), q4 = n % (BW / 4);
        *(int4*)&bs[r][q4 * 4] =
            *(const int4*)(bm32 + (size_t)(rbase + r) * 32 + (j0g >> 5) + q4 * 4);
    }

    const float s1L = s1[hb + gi] * LOG2E;
    const float Arow = s1L;
    const float Brow = s1L * 0.2f;

    short8 ones;
    #pragma unroll
    for (int e = 0; e < 8; ++e) ones[e] = (short)0x3F80;   // bf16 1.0

    f32x4 acc[4];
    #pragma unroll
    for (int fb = 0; fb < 4; ++fb) acc[fb] = (f32x4){0.f, 0.f, 0.f, 0.f};
    f32x4 accs = (f32x4){0.f, 0.f, 0.f, 0.f};

    // write chunk 0 into buf 0; preload chunks 1 and 2; single barrier
    *(int4*)&stage[0][r0][sw] = cva0;
    *(int4*)&stage[0][r0 + 32][sw] = cva1;
    int4 cvb0 = {0, 0, 0, 0}, cvb1 = {0, 0, 0, 0};
    if (1 < NCH) {
        cva0 = *(const int4*)(whb + 64 + ga);
        cva1 = *(const int4*)(whb + 64 + gb);
    }
    if (2 < NCH) {
        cvb0 = *(const int4*)(whb + 128 + ga);
        cvb1 = *(const int4*)(whb + 128 + gb);
    }
    __syncthreads();

    #pragma unroll
    for (int c = 0; c < NCH; ++c) {
        int4 cvc0 = {0, 0, 0, 0}, cvc1 = {0, 0, 0, 0};
        if (c + 3 < NCH) {                          // issue chunk c+3 loads
            const ushort_t* src = whb + (c + 3) * 64;
            cvc0 = *(const int4*)(src + ga);
            cvc1 = *(const int4*)(src + gb);
        }
        #pragma unroll
        for (int ks = 0; ks < 2; ++ks) {
            const int kb = c * 64 + ks * 32 + kg * 8;
            const unsigned byte = (bs[iloc][c * 2 + ks] >> (kg * 8)) & 0xFF;
            const float4 sa = *(const float4*)(s2s + kb);
            const float4 sb = *(const float4*)(s2s + kb + 4);
            const float s2r[8] = {sa.x, sa.y, sa.z, sa.w, sb.x, sb.y, sb.z, sb.w};
            float pv[8];
            #pragma unroll
            for (int e = 0; e < 8; ++e) {
                const float t = s2r[e];
                const float u = Arow + t;
                const float v = __builtin_fmaf(t, 0.2f, Brow);
                float ev = fmaxf(u, v);
                ev = ((byte >> e) & 1) ? ev : -1.0e5f;
                pv[e] = __builtin_amdgcn_exp2f(ev);
            }
            u32x4 pk;
            pk[0] = pkbf(pv[0], pv[1]); pk[1] = pkbf(pv[2], pv[3]);
            pk[2] = pkbf(pv[4], pv[5]); pk[3] = pkbf(pv[6], pv[7]);
            const short8 bfr = __builtin_bit_cast(short8, pk);
            __builtin_amdgcn_s_setprio(1);
            #pragma unroll
            for (int fb = 0; fb < 4; ++fb) {
                const int row = fb * 16 + lo;
                const int slot = (ks * 4 + kg) ^ (row & 7);
                const short8 afr = *(const short8*)&stage[c & 1][row][slot * 4];
                acc[fb] = __builtin_amdgcn_mfma_f32_16x16x32_bf16(afr, bfr, acc[fb], 0, 0, 0);
            }
            accs = __builtin_amdgcn_mfma_f32_16x16x32_bf16(ones, bfr, accs, 0, 0, 0);
            __builtin_amdgcn_s_setprio(0);
        }
        if (c + 1 < NCH) {                          // write landed chunk c+1
            *(int4*)&stage[(c + 1) & 1][r0][sw] = cva0;
            *(int4*)&stage[(c + 1) & 1][r0 + 32][sw] = cva1;
        }
        cva0 = cvb0; cva1 = cvb1;                   // rotate depth-3 registers
        cvb0 = cvc0; cvb1 = cvc1;
        __syncthreads();
    }

    // accs[r] = sum_j P[i=iloc][j] over this block's j-range (all r, all kg)
    // lane (lo,kg) holds i = iloc, f = fb*16 + kg*4 + r
    const float inv = OUT_BF16 ? (1.0f / accs[0]) : 1.0f;
    if (!OUT_BF16 && kg == 0)
        sums[(size_t)jq * (BB * NN) + rbase + iloc] = accs[0];

    unsigned* ot = (unsigned*)ubuf;                // [64][36] u32 view of [64][72] bf16
    #pragma unroll
    for (int fb = 0; fb < 4; ++fb)
        #pragma unroll
        for (int rp = 0; rp < 2; ++rp)
            ot[iloc * 36 + fb * 8 + kg * 2 + rp] =
                pkbf(acc[fb][rp * 2] * inv, acc[fb][rp * 2 + 1] * inv);
    __syncthreads();
    const int i2 = tid >> 2, ch = tid & 3;
    const short8 v0 = *(const short8*)((const short*)ubuf + i2 * 72 + ch * 16);
    const short8 v1 = *(const short8*)((const short*)ubuf + i2 * 72 + ch * 16 + 8);
    if constexpr (OUT_BF16) {
        ushort_t* dst = (ushort_t*)outp + (size_t)(b * NN + it * 64 + i2) * 256 + h * FH + ch * 16;
        *(short8*)dst = v0;
        *(short8*)(dst + 8) = v1;
    } else {
        ushort_t* dst = (ushort_t*)outp + (size_t)jq * (BB * NN * FH)
                      + (size_t)(b * NN + it * 64 + i2) * FH + ch * 16;
        *(short8*)dst = v0;
        *(short8*)(dst + 8) = v1;
    }
}

// ---------------------------------------------------------------------------
// Mean: combine 4 bf16 j-partials, normalize by summed row-sums, ELU,
// partial mean, atomicAdd into (packw-zeroed) out. Grid (16 b, 16 chunks).
// ---------------------------------------------------------------------------
__global__ __launch_bounds__(256) void mean1_kernel(const ushort_t* __restrict__ part,
                                                    const float* __restrict__ sums,
                                                    float* __restrict__ out) {
    const int b = blockIdx.x, ck = blockIdx.y;
    const int tid = threadIdx.x;
    const int f = tid & 63, g = tid >> 6;
    float acc = 0.f;
    #pragma unroll
    for (int i = g; i < 64; i += 4) {
        const int row = b * NN + ck * 64 + i;
        const float srow = sums[row] + sums[row + 16384]
                         + sums[row + 32768] + sums[row + 49152];
        float v = 0.f;
        #pragma unroll
        for (int q = 0; q < 4; ++q)
            v += bf2f((short)part[(size_t)q * 1048576 + (size_t)row * FH + f]);
        v /= srow;
        v = (v > 0.f) ? v : (__builtin_amdgcn_exp2f(v * LOG2E) - 1.0f);
        acc += v;
    }
    __shared__ float r[4][64];
    r[g][f] = acc;
    __syncthreads();
    if (g == 0)
        atomicAdd(&out[b * FH + f],
                  (r[0][f] + r[1][f] + r[2][f] + r[3][f]) * (1.0f / NN));
}

extern "C" void kernel_launch(void* const* d_in, const int* in_sizes, int n_in,
                              void* d_out, int out_size, void* d_ws, size_t ws_size,
                              hipStream_t stream) {
    const float* x       = (const float*)d_in[0];
    const int*   adj     = (const int*)d_in[1];
    const float* W_heads = (const float*)d_in[2];
    const float* a_heads = (const float*)d_in[3];
    const float* W_out   = (const float*)d_in[4];
    const float* a_out   = (const float*)d_in[5];
    float* out = (float*)d_out;
    float* f0  = (float*)d_ws;

    // workspace (float offsets). part (bf16, 8MB) overlays hcat (dead after gemm2).
    ushort_t* hcat  = (ushort_t*)f0;                     // [16384][256] bf16, 8 MB
    ushort_t* part  = (ushort_t*)f0;                     // [4][16384][64] bf16, 8 MB
    ushort_t* WhbT1 = (ushort_t*)(f0 + 2097152);         // [16][256][1024] bf16, 8 MB
    ushort_t* WhbT2 = (ushort_t*)(f0 + 4194304);         // [16][64][1024] bf16, 2 MB
    u64*      bmask = (u64*)(f0 + 4718592);              // [16384][16] u64, 2 MB
    ushort_t* WbT1  = (ushort_t*)(f0 + 5242880);         // [256][256] bf16
    ushort_t* WbT2  = (ushort_t*)(f0 + 5275648);         // [64][256] bf16
    float*    s1_1  = f0 + 5283840;                      // [4][16384]
    float*    s2_1  = s1_1 + 65536;
    float*    s1_2  = s2_1 + 65536;                      // [16384]
    float*    s2_2  = s1_2 + 16384;
    float*    sums2 = s2_2 + 16384;                      // [4][16384]

    dim3 blk(256);

    // weight transpose + out zeroing (adj packing fused into gemm1)
    packw_kernel<<<dim3(320), blk, 0, stream>>>(W_heads, W_out, WbT1, WbT2, out);

    // layer 1 (gemm1 also packs the adjacency bitmask, staggered even/odd)
    gemm_fused<0, 1><<<dim3(4, 256), blk, 0, stream>>>(x, WbT1, a_heads, WhbT1, s1_1, s2_1, 256,
                                                       adj, bmask);
    apply_kernel<NH, 1, 1><<<dim3(1024), blk, 0, stream>>>(WhbT1, 256, s1_1, s2_1,
                                                           (const unsigned*)bmask, hcat, nullptr);

    // layer 2
    gemm_fused<1, 0><<<dim3(1, 256), blk, 0, stream>>>(hcat, WbT2, a_out, WhbT2, s1_2, s2_2, 64,
                                                       nullptr, nullptr);
    apply_kernel<1, 4, 0><<<dim3(1024), blk, 0, stream>>>(WhbT2, 64, s1_2, s2_2,
                                                          (const unsigned*)bmask, part, sums2);

    // combine partials + normalize + elu + mean (atomic tail; out zeroed in packw)
    mean1_kernel<<<dim3(BB, 16), blk, 0, stream>>>(part, sums2, out);
}